// Round 11
// baseline (724.253 us; speedup 1.0000x reference)
//
#include <hip/hip_runtime.h>

// ---------------------------------------------------------------------------
// HardConstrainedMLP: 3-layer MLP -> 100 relaxed DR iterations -> P_eq(P_box)
//   AAT = A A^T + 1e-6 I = L L^T,  G = L^{-1}A (64x256),  b' = L^{-1} b_row
//   corr(w) = (w@G^T - b')@G ;  z += 1.7*(clip(z) - z - corr(2*clip(z)-z))
// R11: R10 + amdgpu_num_vgpr(256): cap the UNIFIED (arch+accum) register
//      allocation at 256 so the wave fits the 2-waves/SIMD tier. Evidence:
//      R10 had 164 arch VGPRs, no spill, LDS 74KB (2 blocks fit) yet still
//      1 wave/SIMD -> AGPR bloat pushed total past 256. Live-set audit ~240.
// ---------------------------------------------------------------------------

typedef float f32x4 __attribute__((ext_vector_type(4)));
typedef float f32x16 __attribute__((ext_vector_type(16)));
typedef unsigned u32x4 __attribute__((ext_vector_type(4)));
typedef short short8 __attribute__((ext_vector_type(8)));

__device__ __forceinline__ unsigned pack_hi(float a, float b) {
  // (bf16bits(b) << 16) | bf16bits(a)
  return __builtin_amdgcn_perm(__float_as_uint(b), __float_as_uint(a), 0x07060302u);
}
__device__ __forceinline__ float trunch(float x) {
  return __uint_as_float(__float_as_uint(x) & 0xFFFF0000u);
}
__device__ __forceinline__ float med3(float x, float lo, float hi) {
  return __builtin_amdgcn_fmed3f(x, lo, hi);
}
__device__ __forceinline__ short8 pack8hi(f32x4 a, f32x4 b) {
  union { unsigned u[4]; short8 v; } H;
  H.u[0] = pack_hi(a[0], a[1]); H.u[1] = pack_hi(a[2], a[3]);
  H.u[2] = pack_hi(b[0], b[1]); H.u[3] = pack_hi(b[2], b[3]);
  return H.v;
}
__device__ __forceinline__ void split2x4(f32x4 a, f32x4 b, short8& hi, short8& lo) {
  union { unsigned u[4]; short8 v; } H, L;
  H.u[0] = pack_hi(a[0], a[1]); H.u[1] = pack_hi(a[2], a[3]);
  H.u[2] = pack_hi(b[0], b[1]); H.u[3] = pack_hi(b[2], b[3]);
  float l0 = a[0] - trunch(a[0]), l1 = a[1] - trunch(a[1]);
  float l2 = a[2] - trunch(a[2]), l3 = a[3] - trunch(a[3]);
  float l4 = b[0] - trunch(b[0]), l5 = b[1] - trunch(b[1]);
  float l6 = b[2] - trunch(b[2]), l7 = b[3] - trunch(b[3]);
  L.u[0] = pack_hi(l0, l1); L.u[1] = pack_hi(l2, l3);
  L.u[2] = pack_hi(l4, l5); L.u[3] = pack_hi(l6, l7);
  hi = H.v; lo = L.v;
}
__device__ __forceinline__ f32x4 mfma16(short8 a, short8 b, f32x4 c) {
  return __builtin_amdgcn_mfma_f32_16x16x32_bf16(a, b, c, 0, 0, 0);
}
__device__ __forceinline__ f32x16 mfma32(short8 a, short8 b, f32x16 c) {
  return __builtin_amdgcn_mfma_f32_32x32x16_bf16(a, b, c, 0, 0, 0);
}

// ---------------- P1: AAT, Cholesky L, Linv, G = Linv @ A -------------------
__global__ __launch_bounds__(512) void prep_kernel(const float* __restrict__ A,
                                                   float* __restrict__ G_out,
                                                   float* __restrict__ LinvT) {
  __shared__ float As[64 * 260];
  __shared__ float T[64 * 65];
  __shared__ float Xi[64 * 65];  // Linv
  const int t = threadIdx.x;

  for (int q = 0; q < 8; ++q) {
    int f = 4 * (t + 512 * q);
    f32x4 v = *(const f32x4*)&A[f];
    int m = f >> 8, d = f & 255;
    *(f32x4*)&As[m * 260 + d] = v;
  }
  __syncthreads();

  for (int q = 0; q < 8; ++q) {
    int f = t + 512 * q;
    int i = f >> 6, j = f & 63;
    float s = 0.f;
    for (int d = 0; d < 256; d += 4) {
      f32x4 xa = *(const f32x4*)&As[i * 260 + d];
      f32x4 xb = *(const f32x4*)&As[j * 260 + d];
      s += xa[0] * xb[0] + xa[1] * xb[1] + xa[2] * xb[2] + xa[3] * xb[3];
    }
    if (i == j) s += 1e-6f;
    T[i * 65 + j] = s;
  }
  __syncthreads();

  if (t < 64) {
    // wave-lockstep Cholesky (lower); lanes 0..63 in one wave
    for (int j = 0; j < 64; ++j) {
      float dj = sqrtf(T[j * 65 + j]);
      float lij = 0.f;
      if (t == j) T[j * 65 + j] = dj;
      if (t > j) { lij = T[t * 65 + j] / dj; T[t * 65 + j] = lij; }
      for (int k = j + 1; k <= t; ++k)
        T[t * 65 + k] -= lij * T[k * 65 + j];
    }
    // Linv: lane t solves L x = e_t (column t)
    for (int i = 0; i < 64; ++i) {
      float s = (i == t) ? 1.f : 0.f;
      for (int j = t; j < i; ++j) s -= T[i * 65 + j] * Xi[j * 65 + t];
      Xi[i * 65 + t] = (i >= t) ? s / T[i * 65 + i] : 0.f;
    }
    for (int i = 0; i < 64; ++i) LinvT[t * 64 + i] = Xi[i * 65 + t];
  }
  __syncthreads();

  // G = Linv @ A: lane-parallel over rows i, wave-uniform broadcast As reads
  {
    const int i = t & 63;    // G row
    const int grp = t >> 6;  // wave id 0..7
    float xrow[64];
#pragma unroll
    for (int j = 0; j < 64; ++j) xrow[j] = Xi[i * 65 + j];
    for (int c = 0; c < 4; ++c) {
      const int d0 = 8 * grp + 64 * c;
      float acc[8] = {};
#pragma unroll
      for (int j = 0; j < 64; ++j) {
        f32x4 a0 = *(const f32x4*)&As[j * 260 + d0];
        f32x4 a1 = *(const f32x4*)&As[j * 260 + d0 + 4];
        float x = xrow[j];
        acc[0] += x * a0[0]; acc[1] += x * a0[1];
        acc[2] += x * a0[2]; acc[3] += x * a0[3];
        acc[4] += x * a1[0]; acc[5] += x * a1[1];
        acc[6] += x * a1[2]; acc[7] += x * a1[3];
      }
      *(f32x4*)&G_out[i * 256 + d0] = (f32x4){acc[0], acc[1], acc[2], acc[3]};
      *(f32x4*)&G_out[i * 256 + d0 + 4] = (f32x4){acc[4], acc[5], acc[6], acc[7]};
    }
  }
}

// ---------------- MLP / bp: fp32 tiled GEMM, 64x128 tile -------------------
__global__ __launch_bounds__(256) void gemm64(const float* __restrict__ X,
                                              const float* __restrict__ W,
                                              const float* __restrict__ bias,
                                              float* __restrict__ Y,
                                              int N, int K, int relu) {
  __shared__ float Xs[8][68];
  __shared__ float Ws[8][132];
  const int t = threadIdx.x;
  const int row0 = blockIdx.x * 64, n0 = blockIdx.y * 128;
  const int ty = t >> 4, tx = t & 15;
  const int xr = t >> 2, xk = (t & 3) * 2;
  const int wk = t >> 5, wn = (t & 31) * 4;
  float acc[4][8] = {};
  for (int kc = 0; kc < K; kc += 8) {
    float2 xv = *(const float2*)&X[(size_t)(row0 + xr) * K + kc + xk];
    f32x4 wv4 = {0.f, 0.f, 0.f, 0.f};
    if (n0 + wn + 4 <= N) {
      wv4 = *(const f32x4*)&W[(size_t)(kc + wk) * N + n0 + wn];
    } else {
#pragma unroll
      for (int e = 0; e < 4; ++e)
        if (n0 + wn + e < N) wv4[e] = W[(size_t)(kc + wk) * N + n0 + wn + e];
    }
    __syncthreads();
    Xs[xk][xr] = xv.x;
    Xs[xk + 1][xr] = xv.y;
    *(f32x4*)&Ws[wk][wn] = wv4;
    __syncthreads();
#pragma unroll
    for (int k = 0; k < 8; ++k) {
      f32x4 a = *(const f32x4*)&Xs[k][ty * 4];
      f32x4 b0 = *(const f32x4*)&Ws[k][tx * 8];
      f32x4 b1 = *(const f32x4*)&Ws[k][tx * 8 + 4];
#pragma unroll
      for (int i = 0; i < 4; ++i) {
        acc[i][0] += a[i] * b0[0]; acc[i][1] += a[i] * b0[1];
        acc[i][2] += a[i] * b0[2]; acc[i][3] += a[i] * b0[3];
        acc[i][4] += a[i] * b1[0]; acc[i][5] += a[i] * b1[1];
        acc[i][6] += a[i] * b1[2]; acc[i][7] += a[i] * b1[3];
      }
    }
  }
#pragma unroll
  for (int i = 0; i < 4; ++i) {
    int row = row0 + ty * 4 + i;
#pragma unroll
    for (int jj = 0; jj < 2; ++jj) {
      int c0 = n0 + tx * 8 + jj * 4;
      if (c0 >= N) continue;
      f32x4 v;
#pragma unroll
      for (int e = 0; e < 4; ++e) {
        float bv = bias ? bias[min(c0 + e, N - 1)] : 0.f;
        v[e] = acc[i][4 * jj + e] + bv;
        if (relu) v[e] = fmaxf(v[e], 0.f);
      }
      if (c0 + 4 <= N) {
        *(f32x4*)&Y[(size_t)row * N + c0] = v;
      } else {
#pragma unroll
        for (int e = 0; e < 4; ++e)
          if (c0 + e < N) Y[(size_t)row * N + c0 + e] = v[e];
      }
    }
  }
}

// ---------------- ITER: fused 100x DR on MFMA ------------------------------
// 512 blocks x 256 thr (4 waves), 32 rows/block, target 2 blocks/CU.
// Per iter: MV1 (w built IN REGISTERS from z via ds_swizzle lane^16) ->
// part st -> bar -> reduce -> rs st -> bar -> MV2 + z-update. 2 barriers.
// GB-lo lives in LDS (glo, bf16 col-major [d][k], XOR granule swizzle).
__global__ __launch_bounds__(256, 1)
__attribute__((amdgpu_num_vgpr(256)))  // cap UNIFIED arch+accum regs: fit the
                                       // 2-waves/SIMD tier (live-set ~240)
void iter_kernel(const float* __restrict__ y0,
                 const float* __restrict__ Gg,
                 const float* __restrict__ bpg,
                 const float* __restrict__ lb,
                 const float* __restrict__ ub,
                 const int* __restrict__ n_iter_p,
                 float* __restrict__ out) {
  __shared__ __align__(16) float part[4 * 32 * 68];  // 34 KB [kq][row][m]
  __shared__ __align__(16) unsigned rs[2 * 32 * 32]; // 8 KB [plane][row][32u32]
  __shared__ __align__(16) short glo[256 * 64];      // 32 KB G-lo bf16 [d][k] swz

  const int t = threadIdx.x, wv = t >> 6, lane = t & 63;
  const int l31 = lane & 31, h = lane >> 5;   // 32x32 lane mapping
  const int lhi = lane >> 4, llo = lane & 15; // 16x16 lane mapping
  const int R0 = blockIdx.x * 32;
  const int n_iter = n_iter_p[0];
  const bool lowhalf = (l31 < 16);

  // ---- glo init: thread t owns column d = t; lo-plane of G, swizzled ----
  {
    const int d = t, r3g = d & 7;
#pragma unroll
    for (int kg = 0; kg < 8; ++kg) {
      u32x4 u;
#pragma unroll
      for (int p = 0; p < 4; ++p) {
        float g0 = Gg[(8 * kg + 2 * p) * 256 + d];
        float g1 = Gg[(8 * kg + 2 * p + 1) * 256 + d];
        u[p] = pack_hi(g0 - trunch(g0), g1 - trunch(g1));
      }
      *(u32x4*)((char*)glo + (d * 128 + ((kg ^ r3g) * 16))) = u;
    }
  }

  // ---- MV1 A-frags (32x32): GA[mt][ks] = G[32mt + l31][64wv + 16ks + 8h + j]
  short8 GAh[2][4], GAl[2][4];
#pragma unroll
  for (int mt = 0; mt < 2; ++mt)
#pragma unroll
    for (int ks = 0; ks < 4; ++ks) {
      const float* gp = &Gg[(32 * mt + l31) * 256 + 64 * wv + 16 * ks + 8 * h];
      split2x4(*(const f32x4*)gp, *(const f32x4*)(gp + 4), GAh[mt][ks], GAl[mt][ks]);
    }
  // ---- MV2 A-frags hi only: GBh[td][ks2] = G[32ks2+8lhi+j][64wv+16td+llo]
  short8 GBh[4][2];
#pragma unroll
  for (int td = 0; td < 4; ++td)
#pragma unroll
    for (int ks2 = 0; ks2 < 2; ++ks2) {
      f32x4 fa, fb;
#pragma unroll
      for (int j = 0; j < 4; ++j) {
        fa[j] = Gg[(32 * ks2 + 8 * lhi + j) * 256 + 64 * wv + 16 * td + llo];
        fb[j] = Gg[(32 * ks2 + 8 * lhi + 4 + j) * 256 + 64 * wv + 16 * td + llo];
      }
      GBh[td][ks2] = pack8hi(fa, fb);
    }

  // ---- bounds (z layout) / b' (reduce layout) ----
  f32x4 lbr[4], ubr[4];
#pragma unroll
  for (int td = 0; td < 4; ++td) {
    lbr[td] = *(const f32x4*)&lb[64 * wv + 16 * td + 4 * lhi];
    ubr[td] = *(const f32x4*)&ub[64 * wv + 16 * td + 4 * lhi];
  }
  const int rrow = t >> 3, m8 = (t & 7) * 8;
  f32x4 bpr0 = *(const f32x4*)&bpg[(R0 + rrow) * 64 + m8];
  f32x4 bpr1 = *(const f32x4*)&bpg[(R0 + rrow) * 64 + m8 + 4];

  // ---- precomputed LDS byte addresses ----
  const int pbase = ((wv * 32 + l31) * 68 + 4 * h) * 4;      // partial store base
  const int prd = (rrow * 68 + m8) * 4;                      // reduce read base
  const int rwr = rrow * 128 + 16 * ((t & 7) ^ (rrow & 7));  // rs write
  int rrd[2][2];  // MV2 rs read
  {
    int r3 = llo & 7;
#pragma unroll
    for (int tr = 0; tr < 2; ++tr)
#pragma unroll
      for (int ks2 = 0; ks2 < 2; ++ks2)
        rrd[tr][ks2] = (16 * tr + llo) * 128 + 16 * ((4 * ks2 + lhi) ^ r3);
  }
  // glo read bases: d-row = 64wv+llo (+ td*2048 imm), granule (4ks2+lhi)^(llo&7)
  const int gl0 = (64 * wv + llo) * 128 + ((lhi ^ (llo & 7)) * 16);
  const int gl1 = (64 * wv + llo) * 128 + (((4 + lhi) ^ (llo & 7)) * 16);

  // ---- z init (w is derived in-register each iteration) ----
  f32x4 z[4][2];
#pragma unroll
  for (int tr = 0; tr < 2; ++tr)
#pragma unroll
    for (int td = 0; td < 4; ++td)
      z[td][tr] = *(const f32x4*)&y0[(R0 + 16 * tr + llo) * 256 + 64 * wv + 16 * td + 4 * lhi];

  for (int it = 0; it <= n_iter; ++it) {
    const bool wlast = (it == n_iter);

    // ---- MV1: partial r^T = G @ w^T over this wave's own k-quarter ----
    // w built from z in regs; cross-row quad exchange via ds_swizzle lane^16.
    f32x16 acc0 = {}, acc1 = {};
#pragma unroll
    for (int ks = 0; ks < 4; ++ks) {
      f32x4 w0, w1, ex, rc, f0, f1;
#pragma unroll
      for (int e = 0; e < 4; ++e) {
        float z0 = z[ks][0][e], z1 = z[ks][1][e];
        float p0 = med3(z0, lbr[ks][e], ubr[ks][e]);
        float p1 = med3(z1, lbr[ks][e], ubr[ks][e]);
        w0[e] = wlast ? p0 : fmaf(2.f, p0, -z0);
        w1[e] = wlast ? p1 : fmaf(2.f, p1, -z1);
        ex[e] = lowhalf ? w1[e] : w0[e];
      }
#pragma unroll
      for (int e = 0; e < 4; ++e)
        rc[e] = __uint_as_float(
            __builtin_amdgcn_ds_swizzle(__float_as_uint(ex[e]), 0x401F));  // xor 16
#pragma unroll
      for (int e = 0; e < 4; ++e) {
        f0[e] = lowhalf ? w0[e] : rc[e];
        f1[e] = lowhalf ? rc[e] : w1[e];
      }
      short8 Bh, Bl;
      split2x4(f0, f1, Bh, Bl);
      __builtin_amdgcn_s_setprio(1);
      acc0 = mfma32(GAh[0][ks], Bh, acc0);
      acc0 = mfma32(GAh[0][ks], Bl, acc0);
      acc0 = mfma32(GAl[0][ks], Bh, acc0);
      acc1 = mfma32(GAh[1][ks], Bh, acc1);
      acc1 = mfma32(GAh[1][ks], Bl, acc1);
      acc1 = mfma32(GAl[1][ks], Bh, acc1);
      __builtin_amdgcn_s_setprio(0);
    }
#pragma unroll
    for (int u = 0; u < 4; ++u) {
      f32x4 q0 = {acc0[4 * u], acc0[4 * u + 1], acc0[4 * u + 2], acc0[4 * u + 3]};
      f32x4 q1 = {acc1[4 * u], acc1[4 * u + 1], acc1[4 * u + 2], acc1[4 * u + 3]};
      *(f32x4*)((char*)part + (pbase + 32 * u)) = q0;
      *(f32x4*)((char*)part + (pbase + 32 * u + 128)) = q1;
    }
    __syncthreads();

    // ---- reduce 4 k-partials, -b', pack to bf16 hi/lo planes ----
    {
      const char* pb = (const char*)part + prd;
      f32x4 s0 = *(const f32x4*)pb;
      f32x4 s1 = *(const f32x4*)(pb + 16);
      s0 += *(const f32x4*)(pb + 8704);  s1 += *(const f32x4*)(pb + 8720);
      s0 += *(const f32x4*)(pb + 17408); s1 += *(const f32x4*)(pb + 17424);
      s0 += *(const f32x4*)(pb + 26112); s1 += *(const f32x4*)(pb + 26128);
      s0 -= bpr0; s1 -= bpr1;
      u32x4 hi4 = {pack_hi(s0[0], s0[1]), pack_hi(s0[2], s0[3]),
                   pack_hi(s1[0], s1[1]), pack_hi(s1[2], s1[3])};
      float l0 = s0[0] - trunch(s0[0]), l1 = s0[1] - trunch(s0[1]);
      float l2 = s0[2] - trunch(s0[2]), l3 = s0[3] - trunch(s0[3]);
      float l4 = s1[0] - trunch(s1[0]), l5 = s1[1] - trunch(s1[1]);
      float l6 = s1[2] - trunch(s1[2]), l7 = s1[3] - trunch(s1[3]);
      u32x4 lo4 = {pack_hi(l0, l1), pack_hi(l2, l3), pack_hi(l4, l5), pack_hi(l6, l7)};
      *(u32x4*)((char*)rs + rwr) = hi4;
      *(u32x4*)((char*)rs + (rwr + 4096)) = lo4;
    }
    __syncthreads();

    // ---- MV2: corr^T = G^T @ r^T (16x16), fused z-update / final store ----
    // GB-lo fragments from glo LDS (hoisted, reused for both row-tiles).
    short8 GBl0[4], GBl1[4];
#pragma unroll
    for (int td = 0; td < 4; ++td) {
      GBl0[td] = *(const short8*)((const char*)glo + (gl0 + td * 2048));
      GBl1[td] = *(const short8*)((const char*)glo + (gl1 + td * 2048));
    }
#pragma unroll
    for (int tr = 0; tr < 2; ++tr) {
      short8 Rh[2], Rl[2];
#pragma unroll
      for (int ks2 = 0; ks2 < 2; ++ks2) {
        Rh[ks2] = *(const short8*)((const char*)rs + rrd[tr][ks2]);
        Rl[ks2] = *(const short8*)((const char*)rs + (rrd[tr][ks2] + 4096));
      }
      f32x4 c[4];
      __builtin_amdgcn_s_setprio(1);
#pragma unroll
      for (int td = 0; td < 4; ++td) {
        f32x4 cc = {};
        cc = mfma16(GBh[td][0], Rh[0], cc);
        cc = mfma16(GBh[td][0], Rl[0], cc);
        cc = mfma16(GBl0[td], Rh[0], cc);
        cc = mfma16(GBh[td][1], Rh[1], cc);
        cc = mfma16(GBh[td][1], Rl[1], cc);
        cc = mfma16(GBl1[td], Rh[1], cc);
        c[td] = cc;
      }
      __builtin_amdgcn_s_setprio(0);

      if (!wlast) {
#pragma unroll
        for (int td = 0; td < 4; ++td) {
          f32x4 zz = z[td][tr], zn;
#pragma unroll
          for (int e = 0; e < 4; ++e) {
            float p = med3(zz[e], lbr[td][e], ubr[td][e]);
            zn[e] = fmaf(1.7f, p - zz[e] - c[td][e], zz[e]);
          }
          z[td][tr] = zn;
        }
      } else {
#pragma unroll
        for (int td = 0; td < 4; ++td) {
          f32x4 zz = z[td][tr], o;
#pragma unroll
          for (int e = 0; e < 4; ++e) {
            float p = med3(zz[e], lbr[td][e], ubr[td][e]);
            o[e] = p - c[td][e];
          }
          *(f32x4*)&out[(R0 + 16 * tr + llo) * 256 + 64 * wv + 16 * td + 4 * lhi] = o;
        }
      }
    }
  }
}

// ---------------------------------------------------------------------------
extern "C" void kernel_launch(void* const* d_in, const int* in_sizes, int n_in,
                              void* d_out, int out_size, void* d_ws, size_t ws_size,
                              hipStream_t stream) {
  (void)in_sizes; (void)n_in; (void)out_size; (void)ws_size;
  const float* x  = (const float*)d_in[0];
  const float* bM = (const float*)d_in[1];
  const float* W1 = (const float*)d_in[2];
  const float* b1 = (const float*)d_in[3];
  const float* W2 = (const float*)d_in[4];
  const float* b2 = (const float*)d_in[5];
  const float* W3 = (const float*)d_in[6];
  const float* b3 = (const float*)d_in[7];
  const float* A  = (const float*)d_in[8];
  const float* lb = (const float*)d_in[9];
  const float* ub = (const float*)d_in[10];
  const int* n_iter = (const int*)d_in[11];
  float* out = (float*)d_out;

  float* ws = (float*)d_ws;
  float* y     = ws;                    // 16384*256
  float* h1    = ws;                    // 16384*200 (overlays y; dead before y)
  float* h2    = y + 16384 * 256;       // 16384*200
  float* bp    = h2 + 16384 * 200;      // 16384*64
  float* G     = bp + 16384 * 64;       // 64*256
  float* LinvT = G + 64 * 256;          // 64*64

  hipLaunchKernelGGL(prep_kernel, dim3(1), dim3(512), 0, stream, A, G, LinvT);
  hipLaunchKernelGGL(gemm64, dim3(256, 1), dim3(256), 0, stream, bM, LinvT, (const float*)nullptr, bp, 64, 64, 0);
  hipLaunchKernelGGL(gemm64, dim3(256, 2), dim3(256), 0, stream, x,  W1, b1, h1, 200, 256, 1);
  hipLaunchKernelGGL(gemm64, dim3(256, 2), dim3(256), 0, stream, h1, W2, b2, h2, 200, 200, 1);
  hipLaunchKernelGGL(gemm64, dim3(256, 2), dim3(256), 0, stream, h2, W3, b3, y,  256, 200, 0);
  hipLaunchKernelGGL(iter_kernel, dim3(512), dim3(256), 0, stream, y, G, bp, lb, ub, n_iter, out);
}

// Round 12
// 603.817 us; speedup vs baseline: 1.1995x; 1.1995x over previous
//
#include <hip/hip_runtime.h>

// ---------------------------------------------------------------------------
// HardConstrainedMLP: 3-layer MLP -> 100 relaxed DR iterations -> P_eq(P_box)
//   AAT = A A^T + 1e-6 I = L L^T,  G = L^{-1}A (64x256),  b' = b @ Linv^T
//   corr(w) = (w@G^T - b')@G ;  z += 1.7*(clip(z) - z - corr(2*clip(z)-z))
// R12: (a) MLP + b' GEMMs moved to 3-split bf16 MFMA (W pre-transposed/split
//      to Wt[n][k] hi/lo planes; activations carried as bf16 hi/lo planes,
//      zero-padded K 200->224; y staged in d_out). (b) iter = R4 body (best
//      measured, 411us) minus the loop-end barrier (R5 dataflow audit:
//      w-exchange is wave-private; 2 barriers/iter).
// ---------------------------------------------------------------------------

typedef float f32x4 __attribute__((ext_vector_type(4)));
typedef float f32x16 __attribute__((ext_vector_type(16)));
typedef unsigned u32x4 __attribute__((ext_vector_type(4)));
typedef short short8 __attribute__((ext_vector_type(8)));

__device__ __forceinline__ unsigned pack_hi(float a, float b) {
  // (bf16bits(b) << 16) | bf16bits(a)
  return __builtin_amdgcn_perm(__float_as_uint(b), __float_as_uint(a), 0x07060302u);
}
__device__ __forceinline__ float trunch(float x) {
  return __uint_as_float(__float_as_uint(x) & 0xFFFF0000u);
}
__device__ __forceinline__ float med3(float x, float lo, float hi) {
  return __builtin_amdgcn_fmed3f(x, lo, hi);
}
__device__ __forceinline__ void split2x4(f32x4 a, f32x4 b, short8& hi, short8& lo) {
  union { unsigned u[4]; short8 v; } H, L;
  H.u[0] = pack_hi(a[0], a[1]); H.u[1] = pack_hi(a[2], a[3]);
  H.u[2] = pack_hi(b[0], b[1]); H.u[3] = pack_hi(b[2], b[3]);
  float l0 = a[0] - trunch(a[0]), l1 = a[1] - trunch(a[1]);
  float l2 = a[2] - trunch(a[2]), l3 = a[3] - trunch(a[3]);
  float l4 = b[0] - trunch(b[0]), l5 = b[1] - trunch(b[1]);
  float l6 = b[2] - trunch(b[2]), l7 = b[3] - trunch(b[3]);
  L.u[0] = pack_hi(l0, l1); L.u[1] = pack_hi(l2, l3);
  L.u[2] = pack_hi(l4, l5); L.u[3] = pack_hi(l6, l7);
  hi = H.v; lo = L.v;
}
__device__ __forceinline__ f32x4 mfma16(short8 a, short8 b, f32x4 c) {
  return __builtin_amdgcn_mfma_f32_16x16x32_bf16(a, b, c, 0, 0, 0);
}
__device__ __forceinline__ f32x16 mfma32(short8 a, short8 b, f32x16 c) {
  return __builtin_amdgcn_mfma_f32_32x32x16_bf16(a, b, c, 0, 0, 0);
}

// ---------------- P1: AAT, Cholesky L, Linv, G = Linv @ A, Wt_bp planes -----
__global__ __launch_bounds__(512) void prep_kernel(const float* __restrict__ A,
                                                   float* __restrict__ G_out,
                                                   unsigned short* __restrict__ Wtbph,
                                                   unsigned short* __restrict__ Wtbpl) {
  __shared__ float As[64 * 260];
  __shared__ float T[64 * 65];
  __shared__ float Xi[64 * 65];  // Linv
  const int t = threadIdx.x;

  for (int q = 0; q < 8; ++q) {
    int f = 4 * (t + 512 * q);
    f32x4 v = *(const f32x4*)&A[f];
    int m = f >> 8, d = f & 255;
    *(f32x4*)&As[m * 260 + d] = v;
  }
  __syncthreads();

  for (int q = 0; q < 8; ++q) {
    int f = t + 512 * q;
    int i = f >> 6, j = f & 63;
    float s = 0.f;
    for (int d = 0; d < 256; d += 4) {
      f32x4 xa = *(const f32x4*)&As[i * 260 + d];
      f32x4 xb = *(const f32x4*)&As[j * 260 + d];
      s += xa[0] * xb[0] + xa[1] * xb[1] + xa[2] * xb[2] + xa[3] * xb[3];
    }
    if (i == j) s += 1e-6f;
    T[i * 65 + j] = s;
  }
  __syncthreads();

  if (t < 64) {
    // wave-lockstep Cholesky (lower); lanes 0..63 in one wave
    for (int j = 0; j < 64; ++j) {
      float dj = sqrtf(T[j * 65 + j]);
      float lij = 0.f;
      if (t == j) T[j * 65 + j] = dj;
      if (t > j) { lij = T[t * 65 + j] / dj; T[t * 65 + j] = lij; }
      for (int k = j + 1; k <= t; ++k)
        T[t * 65 + k] -= lij * T[k * 65 + j];
    }
    // Linv: lane t solves L x = e_t (column t)
    for (int i = 0; i < 64; ++i) {
      float s = (i == t) ? 1.f : 0.f;
      for (int j = t; j < i; ++j) s -= T[i * 65 + j] * Xi[j * 65 + t];
      Xi[i * 65 + t] = (i >= t) ? s / T[i * 65 + i] : 0.f;
    }
    // Wt for bp-gemm: Wt[n=i][k=j] = Linv[i][j], bf16 hi/lo planes
    for (int i = 0; i < 64; ++i) {
      float v = Xi[i * 65 + t];
      unsigned u = __float_as_uint(v);
      Wtbph[i * 64 + t] = (unsigned short)(u >> 16);
      float lo = v - __uint_as_float(u & 0xFFFF0000u);
      Wtbpl[i * 64 + t] = (unsigned short)(__float_as_uint(lo) >> 16);
    }
  }
  __syncthreads();

  // G = Linv @ A: lane-parallel over rows i, wave-uniform broadcast As reads
  {
    const int i = t & 63;
    const int grp = t >> 6;
    float xrow[64];
#pragma unroll
    for (int j = 0; j < 64; ++j) xrow[j] = Xi[i * 65 + j];
    for (int c = 0; c < 4; ++c) {
      const int d0 = 8 * grp + 64 * c;
      float acc[8] = {};
#pragma unroll
      for (int j = 0; j < 64; ++j) {
        f32x4 a0 = *(const f32x4*)&As[j * 260 + d0];
        f32x4 a1 = *(const f32x4*)&As[j * 260 + d0 + 4];
        float x = xrow[j];
        acc[0] += x * a0[0]; acc[1] += x * a0[1];
        acc[2] += x * a0[2]; acc[3] += x * a0[3];
        acc[4] += x * a1[0]; acc[5] += x * a1[1];
        acc[6] += x * a1[2]; acc[7] += x * a1[3];
      }
      *(f32x4*)&G_out[i * 256 + d0] = (f32x4){acc[0], acc[1], acc[2], acc[3]};
      *(f32x4*)&G_out[i * 256 + d0 + 4] = (f32x4){acc[4], acc[5], acc[6], acc[7]};
    }
  }
}

// ---------------- transw: W[K][N] f32 -> Wt[n][k] bf16 hi/lo, zero-padded ---
__global__ __launch_bounds__(256) void transw(const float* __restrict__ W,
                                              unsigned short* __restrict__ Wth,
                                              unsigned short* __restrict__ Wtl,
                                              int K, int N, int KP, int NP) {
  int idx = blockIdx.x * 256 + threadIdx.x;
  if (idx >= NP * KP) return;
  int n = idx / KP, k = idx % KP;
  float v = (n < N && k < K) ? W[k * N + n] : 0.f;
  unsigned u = __float_as_uint(v);
  Wth[idx] = (unsigned short)(u >> 16);
  float lo = v - __uint_as_float(u & 0xFFFF0000u);
  Wtl[idx] = (unsigned short)(__float_as_uint(lo) >> 16);
}

// ---------------- gemm_mfma: Y = act(A @ W + bias), 3-split bf16 MFMA -------
// 64 rows/block, 256 thr (4 waves; wave owns n-tiles wv, wv+4, ...).
// A: f32 (Af) or pre-split bf16 planes (Ah/Al), leading dim lda.
// W: pre-transposed split planes Wt[n][k] (k-contiguous). KPw = 32*ksteps.
// Out: f32 (Yf) or split planes (Yh/Yl), cols [N,NP) written as 0.
__global__ __launch_bounds__(256) void gemm_mfma(
    const float* __restrict__ Af, const unsigned short* __restrict__ Ah,
    const unsigned short* __restrict__ Al, int lda,
    const unsigned short* __restrict__ Wth, const unsigned short* __restrict__ Wtl,
    const float* __restrict__ bias, float* __restrict__ Yf,
    unsigned short* __restrict__ Yh, unsigned short* __restrict__ Yl,
    int ldout, int N, int NP, int ksteps, int relu) {
  __shared__ __align__(16) unsigned short Xh_s[64][40], Xl_s[64][40];
  __shared__ __align__(16) unsigned short Wh_s[256][40], Wl_s[256][40];

  const int t = threadIdx.x, wv = t >> 6, lane = t & 63;
  const int lhi = lane >> 4, llo = lane & 15;
  const int row0 = blockIdx.x * 64;
  const int ntiles = NP >> 4;
  const int KPw = ksteps * 32;
  const int srow = t >> 2, sk8 = (t & 3) * 8;

  f32x4 acc[4][4];
#pragma unroll
  for (int mt = 0; mt < 4; ++mt)
#pragma unroll
    for (int i = 0; i < 4; ++i) acc[mt][i] = (f32x4){0.f, 0.f, 0.f, 0.f};

  for (int kc = 0; kc < ksteps; ++kc) {
    const int k0 = kc * 32;
    if (kc) __syncthreads();
    // ---- stage A tile [64][32] ----
    if (Af) {
      f32x4 v0 = *(const f32x4*)&Af[(size_t)(row0 + srow) * lda + k0 + sk8];
      f32x4 v1 = *(const f32x4*)&Af[(size_t)(row0 + srow) * lda + k0 + sk8 + 4];
      short8 hv, lv;
      split2x4(v0, v1, hv, lv);
      *(short8*)&Xh_s[srow][sk8] = hv;
      *(short8*)&Xl_s[srow][sk8] = lv;
    } else {
      *(short8*)&Xh_s[srow][sk8] = *(const short8*)&Ah[(size_t)(row0 + srow) * lda + k0 + sk8];
      *(short8*)&Xl_s[srow][sk8] = *(const short8*)&Al[(size_t)(row0 + srow) * lda + k0 + sk8];
    }
    // ---- stage Wt tile [NP][32] (t = n row) ----
    if (t < NP) {
      const u32x4* sh = (const u32x4*)&Wth[(size_t)t * KPw + k0];
      const u32x4* sl = (const u32x4*)&Wtl[(size_t)t * KPw + k0];
      u32x4 h0 = sh[0], h1 = sh[1], l0 = sl[0], l1 = sl[1];
      *(u32x4*)&Wh_s[t][0] = h0; *(u32x4*)&Wh_s[t][8] = h1;
      *(u32x4*)&Wl_s[t][0] = l0; *(u32x4*)&Wl_s[t][8] = l1;
      u32x4 h2 = sh[2], h3 = sh[3], l2 = sl[2], l3 = sl[3];
      *(u32x4*)&Wh_s[t][16] = h2; *(u32x4*)&Wh_s[t][24] = h3;
      *(u32x4*)&Wl_s[t][16] = l2; *(u32x4*)&Wl_s[t][24] = l3;
    }
    __syncthreads();
    // ---- compute ----
    short8 Axh[4], Axl[4];
#pragma unroll
    for (int mt = 0; mt < 4; ++mt) {
      Axh[mt] = *(const short8*)&Xh_s[16 * mt + llo][8 * lhi];
      Axl[mt] = *(const short8*)&Xl_s[16 * mt + llo][8 * lhi];
    }
#pragma unroll
    for (int i = 0; i < 4; ++i) {
      int nt = wv + 4 * i;
      if (nt < ntiles) {
        short8 Bh = *(const short8*)&Wh_s[16 * nt + llo][8 * lhi];
        short8 Bl = *(const short8*)&Wl_s[16 * nt + llo][8 * lhi];
#pragma unroll
        for (int mt = 0; mt < 4; ++mt) {
          acc[mt][i] = mfma16(Axh[mt], Bh, acc[mt][i]);
          acc[mt][i] = mfma16(Axl[mt], Bh, acc[mt][i]);
          acc[mt][i] = mfma16(Axh[mt], Bl, acc[mt][i]);
        }
      }
    }
  }

  // ---- epilogue ----
#pragma unroll
  for (int i = 0; i < 4; ++i) {
    int nt = wv + 4 * i;
    if (nt >= ntiles) continue;
    int col = 16 * nt + llo;
    float bv = (bias && col < N) ? bias[col] : 0.f;
#pragma unroll
    for (int mt = 0; mt < 4; ++mt) {
      f32x4 c = acc[mt][i];
      int rowb = row0 + 16 * mt + 4 * lhi;
#pragma unroll
      for (int reg = 0; reg < 4; ++reg) {
        float v = c[reg] + bv;
        if (relu) v = fmaxf(v, 0.f);
        if (col >= N) v = 0.f;
        if (Yf) {
          if (col < N) Yf[(size_t)(rowb + reg) * ldout + col] = v;
        } else {
          unsigned u = __float_as_uint(v);
          float lo = v - __uint_as_float(u & 0xFFFF0000u);
          Yh[(size_t)(rowb + reg) * ldout + col] = (unsigned short)(u >> 16);
          Yl[(size_t)(rowb + reg) * ldout + col] =
              (unsigned short)(__float_as_uint(lo) >> 16);
        }
      }
    }
  }
}

// ---------------- ITER: fused 100x DR on MFMA (R4 body, 2 barriers) --------
// 512 blocks x 256 thr (4 waves), 32 rows/block.
// Loop: MV1 -> part st -> bar -> reduce -> rs st -> bar -> MV2 + z-update +
// next-w write (own d-band; wave-private => no loop-end barrier).
__global__ __launch_bounds__(256) __attribute__((amdgpu_waves_per_eu(2, 2)))
void iter_kernel(const float* __restrict__ y0,
                 const float* __restrict__ Gg,
                 const float* __restrict__ bpg,
                 const float* __restrict__ lb,
                 const float* __restrict__ ub,
                 const int* __restrict__ n_iter_p,
                 float* __restrict__ out) {
  __shared__ __align__(16) float wbuf[32 * 256];     // 32 KB [row][d] f32, granule-XOR
  __shared__ __align__(16) float part[4 * 32 * 68];  // 34 KB [kq][row][m]
  __shared__ __align__(16) unsigned rs[2 * 32 * 32]; // 8 KB [plane][row][32u32], XOR

  const int t = threadIdx.x, wv = t >> 6, lane = t & 63;
  const int l31 = lane & 31, h = lane >> 5;
  const int lhi = lane >> 4, llo = lane & 15;
  const int R0 = blockIdx.x * 32;
  const int n_iter = n_iter_p[0];

  // ---- MV1 A-frags (32x32): GA[mt][ks] = G[32mt + l31][64wv + 16ks + 8h + j]
  short8 GAh[2][4], GAl[2][4];
#pragma unroll
  for (int mt = 0; mt < 2; ++mt)
#pragma unroll
    for (int ks = 0; ks < 4; ++ks) {
      const float* gp = &Gg[(32 * mt + l31) * 256 + 64 * wv + 16 * ks + 8 * h];
      split2x4(*(const f32x4*)gp, *(const f32x4*)(gp + 4), GAh[mt][ks], GAl[mt][ks]);
    }
  // ---- MV2 A-frags (16x16): GB[td][ks2] = G[32ks2 + 8lhi + j][64wv + 16td + llo]
  short8 GBh[4][2], GBl[4][2];
#pragma unroll
  for (int td = 0; td < 4; ++td)
#pragma unroll
    for (int ks2 = 0; ks2 < 2; ++ks2) {
      f32x4 fa, fb;
#pragma unroll
      for (int j = 0; j < 4; ++j) {
        fa[j] = Gg[(32 * ks2 + 8 * lhi + j) * 256 + 64 * wv + 16 * td + llo];
        fb[j] = Gg[(32 * ks2 + 8 * lhi + 4 + j) * 256 + 64 * wv + 16 * td + llo];
      }
      split2x4(fa, fb, GBh[td][ks2], GBl[td][ks2]);
    }

  // ---- bounds (z layout) / b' (reduce layout) ----
  f32x4 lbr[4], ubr[4];
#pragma unroll
  for (int td = 0; td < 4; ++td) {
    lbr[td] = *(const f32x4*)&lb[64 * wv + 16 * td + 4 * lhi];
    ubr[td] = *(const f32x4*)&ub[64 * wv + 16 * td + 4 * lhi];
  }
  const int rrow = t >> 3, m8 = (t & 7) * 8;
  f32x4 bpr0 = *(const f32x4*)&bpg[(R0 + rrow) * 64 + m8];
  f32x4 bpr1 = *(const f32x4*)&bpg[(R0 + rrow) * 64 + m8 + 4];

  // ---- precomputed LDS byte addresses ----
  int waddr[2][4];  // w-write: row = 16tr+llo, granule = (16wv+4td+lhi)^(row&7)
  {
    int r3 = llo & 7;
#pragma unroll
    for (int tr = 0; tr < 2; ++tr)
#pragma unroll
      for (int td = 0; td < 4; ++td)
        waddr[tr][td] = (16 * tr + llo) * 1024 + 16 * (((16 * wv + 4 * td + lhi) ^ r3));
  }
  int raddr[4];  // MV1 w-read: row = l31, granule = (16wv + 4ks + 2h)^(l31&7)
  {
    int r3 = l31 & 7;
#pragma unroll
    for (int ks = 0; ks < 4; ++ks)
      raddr[ks] = l31 * 1024 + 16 * ((16 * wv + 4 * ks + 2 * h) ^ r3);
  }
  const int pbase = ((wv * 32 + l31) * 68 + 4 * h) * 4;
  const int prd = (rrow * 68 + m8) * 4;
  const int rwr = rrow * 128 + 16 * ((t & 7) ^ (rrow & 7));
  int rrd[2][2];
  {
    int r3 = llo & 7;
#pragma unroll
    for (int tr = 0; tr < 2; ++tr)
#pragma unroll
      for (int ks2 = 0; ks2 < 2; ++ks2)
        rrd[tr][ks2] = (16 * tr + llo) * 128 + 16 * ((4 * ks2 + lhi) ^ r3);
  }

  // ---- z init + first w ----
  f32x4 z[4][2];
#pragma unroll
  for (int tr = 0; tr < 2; ++tr)
#pragma unroll
    for (int td = 0; td < 4; ++td) {
      f32x4 v = *(const f32x4*)&y0[(R0 + 16 * tr + llo) * 256 + 64 * wv + 16 * td + 4 * lhi];
      z[td][tr] = v;
      f32x4 wq;
#pragma unroll
      for (int e = 0; e < 4; ++e) {
        float p = med3(v[e], lbr[td][e], ubr[td][e]);
        wq[e] = (n_iter == 0) ? p : fmaf(2.f, p, -v[e]);
      }
      *(f32x4*)((char*)wbuf + waddr[tr][td]) = wq;
    }
  __syncthreads();

  for (int it = 0; it <= n_iter; ++it) {
    // ---- MV1: partial r^T = G @ w^T over this wave's k-quarter ----
    f32x16 acc0 = {}, acc1 = {};
#pragma unroll
    for (int ks = 0; ks < 4; ++ks) {
      f32x4 f0 = *(const f32x4*)((const char*)wbuf + raddr[ks]);
      f32x4 f1 = *(const f32x4*)((const char*)wbuf + (raddr[ks] ^ 16));
      short8 Bh, Bl;
      split2x4(f0, f1, Bh, Bl);
      __builtin_amdgcn_s_setprio(1);
      acc0 = mfma32(GAh[0][ks], Bh, acc0);
      acc0 = mfma32(GAh[0][ks], Bl, acc0);
      acc0 = mfma32(GAl[0][ks], Bh, acc0);
      acc1 = mfma32(GAh[1][ks], Bh, acc1);
      acc1 = mfma32(GAh[1][ks], Bl, acc1);
      acc1 = mfma32(GAl[1][ks], Bh, acc1);
      __builtin_amdgcn_s_setprio(0);
    }
#pragma unroll
    for (int u = 0; u < 4; ++u) {
      f32x4 q0 = {acc0[4 * u], acc0[4 * u + 1], acc0[4 * u + 2], acc0[4 * u + 3]};
      f32x4 q1 = {acc1[4 * u], acc1[4 * u + 1], acc1[4 * u + 2], acc1[4 * u + 3]};
      *(f32x4*)((char*)part + (pbase + 32 * u)) = q0;
      *(f32x4*)((char*)part + (pbase + 32 * u + 128)) = q1;
    }
    __syncthreads();

    // ---- reduce 4 k-partials, -b', pack to bf16 hi/lo planes ----
    {
      const char* pb = (const char*)part + prd;
      f32x4 s0 = *(const f32x4*)pb;
      f32x4 s1 = *(const f32x4*)(pb + 16);
      s0 += *(const f32x4*)(pb + 8704);  s1 += *(const f32x4*)(pb + 8720);
      s0 += *(const f32x4*)(pb + 17408); s1 += *(const f32x4*)(pb + 17424);
      s0 += *(const f32x4*)(pb + 26112); s1 += *(const f32x4*)(pb + 26128);
      s0 -= bpr0; s1 -= bpr1;
      u32x4 hi4 = {pack_hi(s0[0], s0[1]), pack_hi(s0[2], s0[3]),
                   pack_hi(s1[0], s1[1]), pack_hi(s1[2], s1[3])};
      float l0 = s0[0] - trunch(s0[0]), l1 = s0[1] - trunch(s0[1]);
      float l2 = s0[2] - trunch(s0[2]), l3 = s0[3] - trunch(s0[3]);
      float l4 = s1[0] - trunch(s1[0]), l5 = s1[1] - trunch(s1[1]);
      float l6 = s1[2] - trunch(s1[2]), l7 = s1[3] - trunch(s1[3]);
      u32x4 lo4 = {pack_hi(l0, l1), pack_hi(l2, l3), pack_hi(l4, l5), pack_hi(l6, l7)};
      *(u32x4*)((char*)rs + rwr) = hi4;
      *(u32x4*)((char*)rs + (rwr + 4096)) = lo4;
    }
    __syncthreads();

    // ---- MV2: corr^T = G^T @ r^T (16x16); z-update + next-w (own band) ----
#pragma unroll
    for (int tr = 0; tr < 2; ++tr) {
      short8 Rh[2], Rl[2];
#pragma unroll
      for (int ks2 = 0; ks2 < 2; ++ks2) {
        Rh[ks2] = *(const short8*)((const char*)rs + rrd[tr][ks2]);
        Rl[ks2] = *(const short8*)((const char*)rs + (rrd[tr][ks2] + 4096));
      }
      f32x4 c[4];
      __builtin_amdgcn_s_setprio(1);
#pragma unroll
      for (int td = 0; td < 4; ++td) {
        f32x4 cc = {};
        cc = mfma16(GBh[td][0], Rh[0], cc);
        cc = mfma16(GBh[td][0], Rl[0], cc);
        cc = mfma16(GBl[td][0], Rh[0], cc);
        cc = mfma16(GBh[td][1], Rh[1], cc);
        cc = mfma16(GBh[td][1], Rl[1], cc);
        cc = mfma16(GBl[td][1], Rh[1], cc);
        c[td] = cc;
      }
      __builtin_amdgcn_s_setprio(0);

      if (it < n_iter - 1) {
#pragma unroll
        for (int td = 0; td < 4; ++td) {
          f32x4 zz = z[td][tr], zn, wq;
#pragma unroll
          for (int e = 0; e < 4; ++e) {
            float p = med3(zz[e], lbr[td][e], ubr[td][e]);
            zn[e] = fmaf(1.7f, p - zz[e] - c[td][e], zz[e]);
            float pn = med3(zn[e], lbr[td][e], ubr[td][e]);
            wq[e] = fmaf(2.f, pn, -zn[e]);
          }
          z[td][tr] = zn;
          *(f32x4*)((char*)wbuf + waddr[tr][td]) = wq;
        }
      } else if (it == n_iter - 1) {
#pragma unroll
        for (int td = 0; td < 4; ++td) {
          f32x4 zz = z[td][tr], zn, wq;
#pragma unroll
          for (int e = 0; e < 4; ++e) {
            float p = med3(zz[e], lbr[td][e], ubr[td][e]);
            zn[e] = fmaf(1.7f, p - zz[e] - c[td][e], zz[e]);
            wq[e] = med3(zn[e], lbr[td][e], ubr[td][e]);  // w = p on final pass
          }
          z[td][tr] = zn;
          *(f32x4*)((char*)wbuf + waddr[tr][td]) = wq;
        }
      } else {
#pragma unroll
        for (int td = 0; td < 4; ++td) {
          f32x4 zz = z[td][tr], o;
#pragma unroll
          for (int e = 0; e < 4; ++e) {
            float p = med3(zz[e], lbr[td][e], ubr[td][e]);
            o[e] = p - c[td][e];
          }
          *(f32x4*)&out[(R0 + 16 * tr + llo) * 256 + 64 * wv + 16 * td + 4 * lhi] = o;
        }
      }
    }
    // no loop-end barrier: w-write targets this wave's own d-band, read only
    // by this wave's next MV1 (DS ops are wave-in-order); part/rs hazards are
    // covered by the two barriers above (see R5 audit).
  }
}

// ---------------------------------------------------------------------------
extern "C" void kernel_launch(void* const* d_in, const int* in_sizes, int n_in,
                              void* d_out, int out_size, void* d_ws, size_t ws_size,
                              hipStream_t stream) {
  (void)in_sizes; (void)n_in; (void)out_size; (void)ws_size;
  const float* x  = (const float*)d_in[0];
  const float* bM = (const float*)d_in[1];
  const float* W1 = (const float*)d_in[2];
  const float* b1 = (const float*)d_in[3];
  const float* W2 = (const float*)d_in[4];
  const float* b2 = (const float*)d_in[5];
  const float* W3 = (const float*)d_in[6];
  const float* b3 = (const float*)d_in[7];
  const float* A  = (const float*)d_in[8];
  const float* lb = (const float*)d_in[9];
  const float* ub = (const float*)d_in[10];
  const int* n_iter = (const int*)d_in[11];
  float* out = (float*)d_out;

  // workspace layout (bytes)
  char* ws = (char*)d_ws;
  unsigned short* H1h = (unsigned short*)(ws + 0);          // 16384*224*2
  unsigned short* H1l = (unsigned short*)(ws + 7340032);
  unsigned short* H2h = (unsigned short*)(ws + 14680064);
  unsigned short* H2l = (unsigned short*)(ws + 22020096);
  float*          bp  = (float*)(ws + 29360128);            // 16384*64*4
  float*          G   = (float*)(ws + 33554432);            // 64*256*4
  unsigned short* WtAh = (unsigned short*)(ws + 33619968);  // <=224*256*2 (shared)
  unsigned short* WtAl = (unsigned short*)(ws + 33734656);
  unsigned short* Wtbph = (unsigned short*)(ws + 33849344); // 64*64*2
  unsigned short* Wtbpl = (unsigned short*)(ws + 33857536);
  float* y = out;  // stage y in d_out (fully overwritten by iter)

  hipLaunchKernelGGL(prep_kernel, dim3(1), dim3(512), 0, stream, A, G, Wtbph, Wtbpl);

  // layer 1: X[16384][256] @ W1[256][200] -> H1 planes [16384][224]
  hipLaunchKernelGGL(transw, dim3((224 * 256) / 256), dim3(256), 0, stream,
                     W1, WtAh, WtAl, 256, 200, 256, 224);
  hipLaunchKernelGGL(gemm_mfma, dim3(256), dim3(256), 0, stream,
                     x, (const unsigned short*)nullptr, (const unsigned short*)nullptr, 256,
                     WtAh, WtAl, b1, (float*)nullptr, H1h, H1l, 224, 200, 224, 8, 1);
  // layer 2: H1 @ W2[200][200] -> H2 planes
  hipLaunchKernelGGL(transw, dim3((224 * 224 + 255) / 256), dim3(256), 0, stream,
                     W2, WtAh, WtAl, 200, 200, 224, 224);
  hipLaunchKernelGGL(gemm_mfma, dim3(256), dim3(256), 0, stream,
                     (const float*)nullptr, H1h, H1l, 224,
                     WtAh, WtAl, b2, (float*)nullptr, H2h, H2l, 224, 200, 224, 7, 1);
  // layer 3: H2 @ W3[200][256] -> y (= d_out) f32
  hipLaunchKernelGGL(transw, dim3((256 * 224) / 256), dim3(256), 0, stream,
                     W3, WtAh, WtAl, 200, 256, 224, 256);
  hipLaunchKernelGGL(gemm_mfma, dim3(256), dim3(256), 0, stream,
                     (const float*)nullptr, H2h, H2l, 224,
                     WtAh, WtAl, b3, y, (unsigned short*)nullptr, (unsigned short*)nullptr,
                     256, 256, 256, 7, 0);
  // bp = bM[16384][64] @ Linv^T  (Wt = Linv planes)
  hipLaunchKernelGGL(gemm_mfma, dim3(256), dim3(256), 0, stream,
                     bM, (const unsigned short*)nullptr, (const unsigned short*)nullptr, 64,
                     Wtbph, Wtbpl, (const float*)nullptr, bp,
                     (unsigned short*)nullptr, (unsigned short*)nullptr,
                     64, 64, 64, 2, 0);

  hipLaunchKernelGGL(iter_kernel, dim3(512), dim3(256), 0, stream, y, G, bp, lb, ub, n_iter, out);
}

// Round 13
// 581.277 us; speedup vs baseline: 1.2460x; 1.0388x over previous
//
#include <hip/hip_runtime.h>

// ---------------------------------------------------------------------------
// HardConstrainedMLP: 3-layer MLP -> 100 relaxed DR iterations -> P_eq(P_box)
//   AAT = A A^T + 1e-6 I = L L^T,  G = L^{-1}A (64x256),  b' = b @ Linv^T
//   corr(w) = (w@G^T - b')@G ;  z += 1.7*(clip(z) - z - corr(2*clip(z)-z))
// R13: launch-count 10->6. (a) gemm_mfma at 512 thr (8 waves, 2/SIMD TLP);
//      (b) one transw3 kernel for all three weights; (c) bp GEMM folded into
//      iter prologue (12 mfma16/wave, routed via part LDS). iter loop body
//      = R12 (best measured, 380us) unchanged.
// ---------------------------------------------------------------------------

typedef float f32x4 __attribute__((ext_vector_type(4)));
typedef float f32x16 __attribute__((ext_vector_type(16)));
typedef unsigned u32x4 __attribute__((ext_vector_type(4)));
typedef short short8 __attribute__((ext_vector_type(8)));

__device__ __forceinline__ unsigned pack_hi(float a, float b) {
  // (bf16bits(b) << 16) | bf16bits(a)
  return __builtin_amdgcn_perm(__float_as_uint(b), __float_as_uint(a), 0x07060302u);
}
__device__ __forceinline__ float trunch(float x) {
  return __uint_as_float(__float_as_uint(x) & 0xFFFF0000u);
}
__device__ __forceinline__ float med3(float x, float lo, float hi) {
  return __builtin_amdgcn_fmed3f(x, lo, hi);
}
__device__ __forceinline__ void split2x4(f32x4 a, f32x4 b, short8& hi, short8& lo) {
  union { unsigned u[4]; short8 v; } H, L;
  H.u[0] = pack_hi(a[0], a[1]); H.u[1] = pack_hi(a[2], a[3]);
  H.u[2] = pack_hi(b[0], b[1]); H.u[3] = pack_hi(b[2], b[3]);
  float l0 = a[0] - trunch(a[0]), l1 = a[1] - trunch(a[1]);
  float l2 = a[2] - trunch(a[2]), l3 = a[3] - trunch(a[3]);
  float l4 = b[0] - trunch(b[0]), l5 = b[1] - trunch(b[1]);
  float l6 = b[2] - trunch(b[2]), l7 = b[3] - trunch(b[3]);
  L.u[0] = pack_hi(l0, l1); L.u[1] = pack_hi(l2, l3);
  L.u[2] = pack_hi(l4, l5); L.u[3] = pack_hi(l6, l7);
  hi = H.v; lo = L.v;
}
__device__ __forceinline__ f32x4 mfma16(short8 a, short8 b, f32x4 c) {
  return __builtin_amdgcn_mfma_f32_16x16x32_bf16(a, b, c, 0, 0, 0);
}
__device__ __forceinline__ f32x16 mfma32(short8 a, short8 b, f32x16 c) {
  return __builtin_amdgcn_mfma_f32_32x32x16_bf16(a, b, c, 0, 0, 0);
}

// ---------------- P1: AAT, Cholesky L, Linv, G = Linv @ A, Linv planes ------
__global__ __launch_bounds__(512) void prep_kernel(const float* __restrict__ A,
                                                   float* __restrict__ G_out,
                                                   unsigned short* __restrict__ Wtbph,
                                                   unsigned short* __restrict__ Wtbpl) {
  __shared__ float As[64 * 260];
  __shared__ float T[64 * 65];
  __shared__ float Xi[64 * 65];  // Linv
  const int t = threadIdx.x;

  for (int q = 0; q < 8; ++q) {
    int f = 4 * (t + 512 * q);
    f32x4 v = *(const f32x4*)&A[f];
    int m = f >> 8, d = f & 255;
    *(f32x4*)&As[m * 260 + d] = v;
  }
  __syncthreads();

  for (int q = 0; q < 8; ++q) {
    int f = t + 512 * q;
    int i = f >> 6, j = f & 63;
    float s = 0.f;
    for (int d = 0; d < 256; d += 4) {
      f32x4 xa = *(const f32x4*)&As[i * 260 + d];
      f32x4 xb = *(const f32x4*)&As[j * 260 + d];
      s += xa[0] * xb[0] + xa[1] * xb[1] + xa[2] * xb[2] + xa[3] * xb[3];
    }
    if (i == j) s += 1e-6f;
    T[i * 65 + j] = s;
  }
  __syncthreads();

  if (t < 64) {
    for (int j = 0; j < 64; ++j) {
      float dj = sqrtf(T[j * 65 + j]);
      float lij = 0.f;
      if (t == j) T[j * 65 + j] = dj;
      if (t > j) { lij = T[t * 65 + j] / dj; T[t * 65 + j] = lij; }
      for (int k = j + 1; k <= t; ++k)
        T[t * 65 + k] -= lij * T[k * 65 + j];
    }
    for (int i = 0; i < 64; ++i) {
      float s = (i == t) ? 1.f : 0.f;
      for (int j = t; j < i; ++j) s -= T[i * 65 + j] * Xi[j * 65 + t];
      Xi[i * 65 + t] = (i >= t) ? s / T[i * 65 + i] : 0.f;
    }
    // Linv planes for bp-gemm: Wt[n=i][k=t] = Linv[i][t]
    for (int i = 0; i < 64; ++i) {
      float v = Xi[i * 65 + t];
      unsigned u = __float_as_uint(v);
      Wtbph[i * 64 + t] = (unsigned short)(u >> 16);
      float lo = v - __uint_as_float(u & 0xFFFF0000u);
      Wtbpl[i * 64 + t] = (unsigned short)(__float_as_uint(lo) >> 16);
    }
  }
  __syncthreads();

  {
    const int i = t & 63;
    const int grp = t >> 6;
    float xrow[64];
#pragma unroll
    for (int j = 0; j < 64; ++j) xrow[j] = Xi[i * 65 + j];
    for (int c = 0; c < 4; ++c) {
      const int d0 = 8 * grp + 64 * c;
      float acc[8] = {};
#pragma unroll
      for (int j = 0; j < 64; ++j) {
        f32x4 a0 = *(const f32x4*)&As[j * 260 + d0];
        f32x4 a1 = *(const f32x4*)&As[j * 260 + d0 + 4];
        float x = xrow[j];
        acc[0] += x * a0[0]; acc[1] += x * a0[1];
        acc[2] += x * a0[2]; acc[3] += x * a0[3];
        acc[4] += x * a1[0]; acc[5] += x * a1[1];
        acc[6] += x * a1[2]; acc[7] += x * a1[3];
      }
      *(f32x4*)&G_out[i * 256 + d0] = (f32x4){acc[0], acc[1], acc[2], acc[3]};
      *(f32x4*)&G_out[i * 256 + d0 + 4] = (f32x4){acc[4], acc[5], acc[6], acc[7]};
    }
  }
}

// ---------------- transw3: all three W[K][N] -> Wt[n][k] bf16 hi/lo planes --
__global__ __launch_bounds__(256) void transw3(
    const float* __restrict__ W1, const float* __restrict__ W2,
    const float* __restrict__ W3,
    unsigned short* __restrict__ T1h, unsigned short* __restrict__ T1l,
    unsigned short* __restrict__ T2h, unsigned short* __restrict__ T2l,
    unsigned short* __restrict__ T3h, unsigned short* __restrict__ T3l) {
  const int b = blockIdx.x;
  const float* W; unsigned short *Th, *Tl; int K, N, KP, NP, base;
  if (b < 224)      { W = W1; Th = T1h; Tl = T1l; K = 256; N = 200; KP = 256; NP = 224; base = b; }
  else if (b < 420) { W = W2; Th = T2h; Tl = T2l; K = 200; N = 200; KP = 224; NP = 224; base = b - 224; }
  else              { W = W3; Th = T3h; Tl = T3l; K = 200; N = 256; KP = 224; NP = 256; base = b - 420; }
  int idx = base * 256 + threadIdx.x;
  if (idx >= NP * KP) return;
  int n = idx / KP, k = idx - n * KP;
  float v = (n < N && k < K) ? W[k * N + n] : 0.f;
  unsigned u = __float_as_uint(v);
  Th[idx] = (unsigned short)(u >> 16);
  float lo = v - __uint_as_float(u & 0xFFFF0000u);
  Tl[idx] = (unsigned short)(__float_as_uint(lo) >> 16);
}

// ---------------- gemm_mfma: Y = act(A @ W + bias), 3-split bf16 MFMA -------
// 64 rows/block, 512 thr (8 waves, 2/SIMD); wave owns n-tiles {wv, wv+8}.
__global__ __launch_bounds__(512) void gemm_mfma(
    const float* __restrict__ Af, const unsigned short* __restrict__ Ah,
    const unsigned short* __restrict__ Al, int lda,
    const unsigned short* __restrict__ Wth, const unsigned short* __restrict__ Wtl,
    const float* __restrict__ bias, float* __restrict__ Yf,
    unsigned short* __restrict__ Yh, unsigned short* __restrict__ Yl,
    int ldout, int N, int NP, int ksteps, int relu) {
  __shared__ __align__(16) unsigned short Xh_s[64][40], Xl_s[64][40];
  __shared__ __align__(16) unsigned short Wh_s[256][40], Wl_s[256][40];

  const int t = threadIdx.x, wv = t >> 6, lane = t & 63;
  const int lhi = lane >> 4, llo = lane & 15;
  const int row0 = blockIdx.x * 64;
  const int ntiles = NP >> 4;
  const int KPw = ksteps * 32;
  const int srow = t >> 2, sk8 = (t & 3) * 8;  // X stage (t < 256)
  const int wn = t >> 1, wh = (t & 1) * 16;    // W stage (all 512)

  f32x4 acc[4][2];
#pragma unroll
  for (int mt = 0; mt < 4; ++mt)
#pragma unroll
    for (int i = 0; i < 2; ++i) acc[mt][i] = (f32x4){0.f, 0.f, 0.f, 0.f};

  for (int kc = 0; kc < ksteps; ++kc) {
    const int k0 = kc * 32;
    if (kc) __syncthreads();
    if (t < 256) {
      if (Af) {
        f32x4 v0 = *(const f32x4*)&Af[(size_t)(row0 + srow) * lda + k0 + sk8];
        f32x4 v1 = *(const f32x4*)&Af[(size_t)(row0 + srow) * lda + k0 + sk8 + 4];
        short8 hv, lv;
        split2x4(v0, v1, hv, lv);
        *(short8*)&Xh_s[srow][sk8] = hv;
        *(short8*)&Xl_s[srow][sk8] = lv;
      } else {
        *(short8*)&Xh_s[srow][sk8] = *(const short8*)&Ah[(size_t)(row0 + srow) * lda + k0 + sk8];
        *(short8*)&Xl_s[srow][sk8] = *(const short8*)&Al[(size_t)(row0 + srow) * lda + k0 + sk8];
      }
    }
    if (wn < NP) {
      const u32x4* sh = (const u32x4*)&Wth[(size_t)wn * KPw + k0 + wh];
      const u32x4* sl = (const u32x4*)&Wtl[(size_t)wn * KPw + k0 + wh];
      u32x4 h0 = sh[0], h1 = sh[1], l0 = sl[0], l1 = sl[1];
      *(u32x4*)&Wh_s[wn][wh] = h0; *(u32x4*)&Wh_s[wn][wh + 8] = h1;
      *(u32x4*)&Wl_s[wn][wh] = l0; *(u32x4*)&Wl_s[wn][wh + 8] = l1;
    }
    __syncthreads();
    short8 Axh[4], Axl[4];
#pragma unroll
    for (int mt = 0; mt < 4; ++mt) {
      Axh[mt] = *(const short8*)&Xh_s[16 * mt + llo][8 * lhi];
      Axl[mt] = *(const short8*)&Xl_s[16 * mt + llo][8 * lhi];
    }
#pragma unroll
    for (int i = 0; i < 2; ++i) {
      int nt = wv + 8 * i;
      if (nt < ntiles) {
        short8 Bh = *(const short8*)&Wh_s[16 * nt + llo][8 * lhi];
        short8 Bl = *(const short8*)&Wl_s[16 * nt + llo][8 * lhi];
#pragma unroll
        for (int mt = 0; mt < 4; ++mt) {
          acc[mt][i] = mfma16(Axh[mt], Bh, acc[mt][i]);
          acc[mt][i] = mfma16(Axl[mt], Bh, acc[mt][i]);
          acc[mt][i] = mfma16(Axh[mt], Bl, acc[mt][i]);
        }
      }
    }
  }

#pragma unroll
  for (int i = 0; i < 2; ++i) {
    int nt = wv + 8 * i;
    if (nt >= ntiles) continue;
    int col = 16 * nt + llo;
    float bv = (bias && col < N) ? bias[col] : 0.f;
#pragma unroll
    for (int mt = 0; mt < 4; ++mt) {
      f32x4 c = acc[mt][i];
      int rowb = row0 + 16 * mt + 4 * lhi;
#pragma unroll
      for (int reg = 0; reg < 4; ++reg) {
        float v = c[reg] + bv;
        if (relu) v = fmaxf(v, 0.f);
        if (col >= N) v = 0.f;
        if (Yf) {
          if (col < N) Yf[(size_t)(rowb + reg) * ldout + col] = v;
        } else {
          unsigned u = __float_as_uint(v);
          float lo = v - __uint_as_float(u & 0xFFFF0000u);
          Yh[(size_t)(rowb + reg) * ldout + col] = (unsigned short)(u >> 16);
          Yl[(size_t)(rowb + reg) * ldout + col] =
              (unsigned short)(__float_as_uint(lo) >> 16);
        }
      }
    }
  }
}

// ---------------- ITER: fused 100x DR on MFMA (R12 body + bp prologue) -----
__global__ __launch_bounds__(256) __attribute__((amdgpu_waves_per_eu(2, 2)))
void iter_kernel(const float* __restrict__ y0,
                 const float* __restrict__ Gg,
                 const float* __restrict__ bMg,
                 const unsigned short* __restrict__ Wtbph,
                 const unsigned short* __restrict__ Wtbpl,
                 const float* __restrict__ lb,
                 const float* __restrict__ ub,
                 const int* __restrict__ n_iter_p,
                 float* __restrict__ out) {
  __shared__ __align__(16) float wbuf[32 * 256];     // 32 KB [row][d] f32, granule-XOR
  __shared__ __align__(16) float part[4 * 32 * 68];  // 34 KB [kq][row][m]
  __shared__ __align__(16) unsigned rs[2 * 32 * 32]; // 8 KB [plane][row][32u32], XOR

  const int t = threadIdx.x, wv = t >> 6, lane = t & 63;
  const int l31 = lane & 31, h = lane >> 5;
  const int lhi = lane >> 4, llo = lane & 15;
  const int R0 = blockIdx.x * 32;
  const int n_iter = n_iter_p[0];

  // ---- bp prologue: bp[32][64] = bM[R0..][64] @ Linv^T via mfma16 ----
  f32x4 bcc[2];
  bcc[0] = (f32x4){0.f, 0.f, 0.f, 0.f};
  bcc[1] = (f32x4){0.f, 0.f, 0.f, 0.f};
#pragma unroll
  for (int ks = 0; ks < 2; ++ks) {
    short8 Bh = *(const short8*)&Wtbph[(16 * wv + llo) * 64 + 32 * ks + 8 * lhi];
    short8 Bl = *(const short8*)&Wtbpl[(16 * wv + llo) * 64 + 32 * ks + 8 * lhi];
#pragma unroll
    for (int mt = 0; mt < 2; ++mt) {
      const float* ap = &bMg[(size_t)(R0 + 16 * mt + llo) * 64 + 32 * ks + 8 * lhi];
      short8 Ah_, Al_;
      split2x4(*(const f32x4*)ap, *(const f32x4*)(ap + 4), Ah_, Al_);
      bcc[mt] = mfma16(Ah_, Bh, bcc[mt]);
      bcc[mt] = mfma16(Al_, Bh, bcc[mt]);
      bcc[mt] = mfma16(Ah_, Bl, bcc[mt]);
    }
  }
#pragma unroll
  for (int mt = 0; mt < 2; ++mt)
#pragma unroll
    for (int reg = 0; reg < 4; ++reg)
      part[(16 * mt + 4 * lhi + reg) * 64 + 16 * wv + llo] = bcc[mt][reg];
  __syncthreads();
  const int rrow = t >> 3, m8 = (t & 7) * 8;
  f32x4 bpr0 = *(const f32x4*)&part[rrow * 64 + m8];
  f32x4 bpr1 = *(const f32x4*)&part[rrow * 64 + m8 + 4];

  // ---- MV1 A-frags (32x32): GA[mt][ks] = G[32mt + l31][64wv + 16ks + 8h + j]
  short8 GAh[2][4], GAl[2][4];
#pragma unroll
  for (int mt = 0; mt < 2; ++mt)
#pragma unroll
    for (int ks = 0; ks < 4; ++ks) {
      const float* gp = &Gg[(32 * mt + l31) * 256 + 64 * wv + 16 * ks + 8 * h];
      split2x4(*(const f32x4*)gp, *(const f32x4*)(gp + 4), GAh[mt][ks], GAl[mt][ks]);
    }
  // ---- MV2 A-frags (16x16): GB[td][ks2] = G[32ks2 + 8lhi + j][64wv + 16td + llo]
  short8 GBh[4][2], GBl[4][2];
#pragma unroll
  for (int td = 0; td < 4; ++td)
#pragma unroll
    for (int ks2 = 0; ks2 < 2; ++ks2) {
      f32x4 fa, fb;
#pragma unroll
      for (int j = 0; j < 4; ++j) {
        fa[j] = Gg[(32 * ks2 + 8 * lhi + j) * 256 + 64 * wv + 16 * td + llo];
        fb[j] = Gg[(32 * ks2 + 8 * lhi + 4 + j) * 256 + 64 * wv + 16 * td + llo];
      }
      split2x4(fa, fb, GBh[td][ks2], GBl[td][ks2]);
    }

  // ---- bounds (z layout) ----
  f32x4 lbr[4], ubr[4];
#pragma unroll
  for (int td = 0; td < 4; ++td) {
    lbr[td] = *(const f32x4*)&lb[64 * wv + 16 * td + 4 * lhi];
    ubr[td] = *(const f32x4*)&ub[64 * wv + 16 * td + 4 * lhi];
  }

  // ---- precomputed LDS byte addresses ----
  int waddr[2][4];
  {
    int r3 = llo & 7;
#pragma unroll
    for (int tr = 0; tr < 2; ++tr)
#pragma unroll
      for (int td = 0; td < 4; ++td)
        waddr[tr][td] = (16 * tr + llo) * 1024 + 16 * (((16 * wv + 4 * td + lhi) ^ r3));
  }
  int raddr[4];
  {
    int r3 = l31 & 7;
#pragma unroll
    for (int ks = 0; ks < 4; ++ks)
      raddr[ks] = l31 * 1024 + 16 * ((16 * wv + 4 * ks + 2 * h) ^ r3);
  }
  const int pbase = ((wv * 32 + l31) * 68 + 4 * h) * 4;
  const int prd = (rrow * 68 + m8) * 4;
  const int rwr = rrow * 128 + 16 * ((t & 7) ^ (rrow & 7));
  int rrd[2][2];
  {
    int r3 = llo & 7;
#pragma unroll
    for (int tr = 0; tr < 2; ++tr)
#pragma unroll
      for (int ks2 = 0; ks2 < 2; ++ks2)
        rrd[tr][ks2] = (16 * tr + llo) * 128 + 16 * ((4 * ks2 + lhi) ^ r3);
  }

  // ---- z init + first w ----
  f32x4 z[4][2];
#pragma unroll
  for (int tr = 0; tr < 2; ++tr)
#pragma unroll
    for (int td = 0; td < 4; ++td) {
      f32x4 v = *(const f32x4*)&y0[(R0 + 16 * tr + llo) * 256 + 64 * wv + 16 * td + 4 * lhi];
      z[td][tr] = v;
      f32x4 wq;
#pragma unroll
      for (int e = 0; e < 4; ++e) {
        float p = med3(v[e], lbr[td][e], ubr[td][e]);
        wq[e] = (n_iter == 0) ? p : fmaf(2.f, p, -v[e]);
      }
      *(f32x4*)((char*)wbuf + waddr[tr][td]) = wq;
    }
  __syncthreads();  // also orders bpr reads before loop's part stores

  for (int it = 0; it <= n_iter; ++it) {
    // ---- MV1: partial r^T = G @ w^T over this wave's k-quarter ----
    f32x16 acc0 = {}, acc1 = {};
#pragma unroll
    for (int ks = 0; ks < 4; ++ks) {
      f32x4 f0 = *(const f32x4*)((const char*)wbuf + raddr[ks]);
      f32x4 f1 = *(const f32x4*)((const char*)wbuf + (raddr[ks] ^ 16));
      short8 Bh, Bl;
      split2x4(f0, f1, Bh, Bl);
      __builtin_amdgcn_s_setprio(1);
      acc0 = mfma32(GAh[0][ks], Bh, acc0);
      acc0 = mfma32(GAh[0][ks], Bl, acc0);
      acc0 = mfma32(GAl[0][ks], Bh, acc0);
      acc1 = mfma32(GAh[1][ks], Bh, acc1);
      acc1 = mfma32(GAh[1][ks], Bl, acc1);
      acc1 = mfma32(GAl[1][ks], Bh, acc1);
      __builtin_amdgcn_s_setprio(0);
    }
#pragma unroll
    for (int u = 0; u < 4; ++u) {
      f32x4 q0 = {acc0[4 * u], acc0[4 * u + 1], acc0[4 * u + 2], acc0[4 * u + 3]};
      f32x4 q1 = {acc1[4 * u], acc1[4 * u + 1], acc1[4 * u + 2], acc1[4 * u + 3]};
      *(f32x4*)((char*)part + (pbase + 32 * u)) = q0;
      *(f32x4*)((char*)part + (pbase + 32 * u + 128)) = q1;
    }
    __syncthreads();

    // ---- reduce 4 k-partials, -b', pack to bf16 hi/lo planes ----
    {
      const char* pb = (const char*)part + prd;
      f32x4 s0 = *(const f32x4*)pb;
      f32x4 s1 = *(const f32x4*)(pb + 16);
      s0 += *(const f32x4*)(pb + 8704);  s1 += *(const f32x4*)(pb + 8720);
      s0 += *(const f32x4*)(pb + 17408); s1 += *(const f32x4*)(pb + 17424);
      s0 += *(const f32x4*)(pb + 26112); s1 += *(const f32x4*)(pb + 26128);
      s0 -= bpr0; s1 -= bpr1;
      u32x4 hi4 = {pack_hi(s0[0], s0[1]), pack_hi(s0[2], s0[3]),
                   pack_hi(s1[0], s1[1]), pack_hi(s1[2], s1[3])};
      float l0 = s0[0] - trunch(s0[0]), l1 = s0[1] - trunch(s0[1]);
      float l2 = s0[2] - trunch(s0[2]), l3 = s0[3] - trunch(s0[3]);
      float l4 = s1[0] - trunch(s1[0]), l5 = s1[1] - trunch(s1[1]);
      float l6 = s1[2] - trunch(s1[2]), l7 = s1[3] - trunch(s1[3]);
      u32x4 lo4 = {pack_hi(l0, l1), pack_hi(l2, l3), pack_hi(l4, l5), pack_hi(l6, l7)};
      *(u32x4*)((char*)rs + rwr) = hi4;
      *(u32x4*)((char*)rs + (rwr + 4096)) = lo4;
    }
    __syncthreads();

    // ---- MV2: corr^T = G^T @ r^T (16x16); z-update + next-w (own band) ----
#pragma unroll
    for (int tr = 0; tr < 2; ++tr) {
      short8 Rh[2], Rl[2];
#pragma unroll
      for (int ks2 = 0; ks2 < 2; ++ks2) {
        Rh[ks2] = *(const short8*)((const char*)rs + rrd[tr][ks2]);
        Rl[ks2] = *(const short8*)((const char*)rs + (rrd[tr][ks2] + 4096));
      }
      f32x4 c[4];
      __builtin_amdgcn_s_setprio(1);
#pragma unroll
      for (int td = 0; td < 4; ++td) {
        f32x4 cc = {};
        cc = mfma16(GBh[td][0], Rh[0], cc);
        cc = mfma16(GBh[td][0], Rl[0], cc);
        cc = mfma16(GBl[td][0], Rh[0], cc);
        cc = mfma16(GBh[td][1], Rh[1], cc);
        cc = mfma16(GBh[td][1], Rl[1], cc);
        cc = mfma16(GBl[td][1], Rh[1], cc);
        c[td] = cc;
      }
      __builtin_amdgcn_s_setprio(0);

      if (it < n_iter - 1) {
#pragma unroll
        for (int td = 0; td < 4; ++td) {
          f32x4 zz = z[td][tr], zn, wq;
#pragma unroll
          for (int e = 0; e < 4; ++e) {
            float p = med3(zz[e], lbr[td][e], ubr[td][e]);
            zn[e] = fmaf(1.7f, p - zz[e] - c[td][e], zz[e]);
            float pn = med3(zn[e], lbr[td][e], ubr[td][e]);
            wq[e] = fmaf(2.f, pn, -zn[e]);
          }
          z[td][tr] = zn;
          *(f32x4*)((char*)wbuf + waddr[tr][td]) = wq;
        }
      } else if (it == n_iter - 1) {
#pragma unroll
        for (int td = 0; td < 4; ++td) {
          f32x4 zz = z[td][tr], zn, wq;
#pragma unroll
          for (int e = 0; e < 4; ++e) {
            float p = med3(zz[e], lbr[td][e], ubr[td][e]);
            zn[e] = fmaf(1.7f, p - zz[e] - c[td][e], zz[e]);
            wq[e] = med3(zn[e], lbr[td][e], ubr[td][e]);  // w = p on final pass
          }
          z[td][tr] = zn;
          *(f32x4*)((char*)wbuf + waddr[tr][td]) = wq;
        }
      } else {
#pragma unroll
        for (int td = 0; td < 4; ++td) {
          f32x4 zz = z[td][tr], o;
#pragma unroll
          for (int e = 0; e < 4; ++e) {
            float p = med3(zz[e], lbr[td][e], ubr[td][e]);
            o[e] = p - c[td][e];
          }
          *(f32x4*)&out[(R0 + 16 * tr + llo) * 256 + 64 * wv + 16 * td + 4 * lhi] = o;
        }
      }
    }
    // no loop-end barrier (w-exchange is wave-private; see R5/R12 audit)
  }
}

// ---------------------------------------------------------------------------
extern "C" void kernel_launch(void* const* d_in, const int* in_sizes, int n_in,
                              void* d_out, int out_size, void* d_ws, size_t ws_size,
                              hipStream_t stream) {
  (void)in_sizes; (void)n_in; (void)out_size; (void)ws_size;
  const float* x  = (const float*)d_in[0];
  const float* bM = (const float*)d_in[1];
  const float* W1 = (const float*)d_in[2];
  const float* b1 = (const float*)d_in[3];
  const float* W2 = (const float*)d_in[4];
  const float* b2 = (const float*)d_in[5];
  const float* W3 = (const float*)d_in[6];
  const float* b3 = (const float*)d_in[7];
  const float* A  = (const float*)d_in[8];
  const float* lb = (const float*)d_in[9];
  const float* ub = (const float*)d_in[10];
  const int* n_iter = (const int*)d_in[11];
  float* out = (float*)d_out;

  // workspace layout (bytes)
  char* ws = (char*)d_ws;
  unsigned short* H1h  = (unsigned short*)(ws + 0);         // 16384*224*2
  unsigned short* H1l  = (unsigned short*)(ws + 7340032);
  unsigned short* H2h  = (unsigned short*)(ws + 14680064);
  unsigned short* H2l  = (unsigned short*)(ws + 22020096);
  float*          G    = (float*)(ws + 29360128);           // 64*256*4
  unsigned short* Wt1h = (unsigned short*)(ws + 29425664);  // 224*256*2
  unsigned short* Wt1l = (unsigned short*)(ws + 29540352);
  unsigned short* Wt2h = (unsigned short*)(ws + 29655040);  // 224*224*2
  unsigned short* Wt2l = (unsigned short*)(ws + 29755392);
  unsigned short* Wt3h = (unsigned short*)(ws + 29855744);  // 256*224*2
  unsigned short* Wt3l = (unsigned short*)(ws + 29970432);
  unsigned short* Wtbph = (unsigned short*)(ws + 30085120); // 64*64*2
  unsigned short* Wtbpl = (unsigned short*)(ws + 30093312);
  float* y = out;  // stage y in d_out (fully overwritten by iter)

  hipLaunchKernelGGL(prep_kernel, dim3(1), dim3(512), 0, stream, A, G, Wtbph, Wtbpl);
  hipLaunchKernelGGL(transw3, dim3(644), dim3(256), 0, stream,
                     W1, W2, W3, Wt1h, Wt1l, Wt2h, Wt2l, Wt3h, Wt3l);

  // layer 1: x[16384][256] @ W1 -> H1 planes [16384][224]
  hipLaunchKernelGGL(gemm_mfma, dim3(256), dim3(512), 0, stream,
                     x, (const unsigned short*)nullptr, (const unsigned short*)nullptr, 256,
                     Wt1h, Wt1l, b1, (float*)nullptr, H1h, H1l, 224, 200, 224, 8, 1);
  // layer 2: H1 @ W2 -> H2 planes
  hipLaunchKernelGGL(gemm_mfma, dim3(256), dim3(512), 0, stream,
                     (const float*)nullptr, H1h, H1l, 224,
                     Wt2h, Wt2l, b2, (float*)nullptr, H2h, H2l, 224, 200, 224, 7, 1);
  // layer 3: H2 @ W3 -> y (= d_out) f32
  hipLaunchKernelGGL(gemm_mfma, dim3(256), dim3(512), 0, stream,
                     (const float*)nullptr, H2h, H2l, 224,
                     Wt3h, Wt3l, b3, y, (unsigned short*)nullptr, (unsigned short*)nullptr,
                     256, 256, 256, 7, 0);

  hipLaunchKernelGGL(iter_kernel, dim3(512), dim3(256), 0, stream,
                     y, G, bM, Wtbph, Wtbpl, lb, ub, n_iter, out);
}

// Round 14
// 579.910 us; speedup vs baseline: 1.2489x; 1.0024x over previous
//
#include <hip/hip_runtime.h>

// ---------------------------------------------------------------------------
// HardConstrainedMLP: 3-layer MLP -> 100 relaxed DR iterations -> P_eq(P_box)
//   AAT = A A^T + 1e-6 I = L L^T,  G = L^{-1}A (64x256),  b' = b @ Linv^T
//   corr(w) = (w@G^T - b')@G ;  z += 1.7*(clip(z) - z - corr(2*clip(z)-z))
// R14: non-iter section. (a) gemm_mfma v2: 512 blocks x 32 rows -> 2 blk/CU,
//      16 waves/CU TLP; (b) prep fused into transw kernel (block 0) -> 5
//      launches. iter = R13 body unchanged (383us verified).
// ---------------------------------------------------------------------------

typedef float f32x4 __attribute__((ext_vector_type(4)));
typedef float f32x16 __attribute__((ext_vector_type(16)));
typedef unsigned u32x4 __attribute__((ext_vector_type(4)));
typedef short short8 __attribute__((ext_vector_type(8)));

__device__ __forceinline__ unsigned pack_hi(float a, float b) {
  // (bf16bits(b) << 16) | bf16bits(a)
  return __builtin_amdgcn_perm(__float_as_uint(b), __float_as_uint(a), 0x07060302u);
}
__device__ __forceinline__ float trunch(float x) {
  return __uint_as_float(__float_as_uint(x) & 0xFFFF0000u);
}
__device__ __forceinline__ float med3(float x, float lo, float hi) {
  return __builtin_amdgcn_fmed3f(x, lo, hi);
}
__device__ __forceinline__ void split2x4(f32x4 a, f32x4 b, short8& hi, short8& lo) {
  union { unsigned u[4]; short8 v; } H, L;
  H.u[0] = pack_hi(a[0], a[1]); H.u[1] = pack_hi(a[2], a[3]);
  H.u[2] = pack_hi(b[0], b[1]); H.u[3] = pack_hi(b[2], b[3]);
  float l0 = a[0] - trunch(a[0]), l1 = a[1] - trunch(a[1]);
  float l2 = a[2] - trunch(a[2]), l3 = a[3] - trunch(a[3]);
  float l4 = b[0] - trunch(b[0]), l5 = b[1] - trunch(b[1]);
  float l6 = b[2] - trunch(b[2]), l7 = b[3] - trunch(b[3]);
  L.u[0] = pack_hi(l0, l1); L.u[1] = pack_hi(l2, l3);
  L.u[2] = pack_hi(l4, l5); L.u[3] = pack_hi(l6, l7);
  hi = H.v; lo = L.v;
}
__device__ __forceinline__ f32x4 mfma16(short8 a, short8 b, f32x4 c) {
  return __builtin_amdgcn_mfma_f32_16x16x32_bf16(a, b, c, 0, 0, 0);
}
__device__ __forceinline__ f32x16 mfma32(short8 a, short8 b, f32x16 c) {
  return __builtin_amdgcn_mfma_f32_32x32x16_bf16(a, b, c, 0, 0, 0);
}

// ---------------- fused prep (block 0) + weight transpose (blocks 1..) ------
// prep: AAT, Cholesky L, Linv, G = Linv @ A, Linv bf16 planes.
// transw: W[K][N] f32 -> Wt[n][k] bf16 hi/lo planes, zero-padded.
__global__ __launch_bounds__(512) void prep_transw(
    const float* __restrict__ A, float* __restrict__ G_out,
    unsigned short* __restrict__ Wtbph, unsigned short* __restrict__ Wtbpl,
    const float* __restrict__ W1, const float* __restrict__ W2,
    const float* __restrict__ W3,
    unsigned short* __restrict__ T1h, unsigned short* __restrict__ T1l,
    unsigned short* __restrict__ T2h, unsigned short* __restrict__ T2l,
    unsigned short* __restrict__ T3h, unsigned short* __restrict__ T3l) {
  const int t = threadIdx.x;
  if (blockIdx.x != 0) {
    const int b = blockIdx.x - 1;
    const float* W; unsigned short *Th, *Tl; int K, N, KP, NP, base;
    if (b < 112)      { W = W1; Th = T1h; Tl = T1l; K = 256; N = 200; KP = 256; NP = 224; base = b; }
    else if (b < 210) { W = W2; Th = T2h; Tl = T2l; K = 200; N = 200; KP = 224; NP = 224; base = b - 112; }
    else              { W = W3; Th = T3h; Tl = T3l; K = 200; N = 256; KP = 224; NP = 256; base = b - 210; }
    int idx = base * 512 + t;
    if (idx >= NP * KP) return;
    int n = idx / KP, k = idx - n * KP;
    float v = (n < N && k < K) ? W[k * N + n] : 0.f;
    unsigned u = __float_as_uint(v);
    Th[idx] = (unsigned short)(u >> 16);
    float lo = v - __uint_as_float(u & 0xFFFF0000u);
    Tl[idx] = (unsigned short)(__float_as_uint(lo) >> 16);
    return;
  }

  __shared__ float As[64 * 260];
  __shared__ float T[64 * 65];
  __shared__ float Xi[64 * 65];  // Linv

  for (int q = 0; q < 8; ++q) {
    int f = 4 * (t + 512 * q);
    f32x4 v = *(const f32x4*)&A[f];
    int m = f >> 8, d = f & 255;
    *(f32x4*)&As[m * 260 + d] = v;
  }
  __syncthreads();

  for (int q = 0; q < 8; ++q) {
    int f = t + 512 * q;
    int i = f >> 6, j = f & 63;
    float s = 0.f;
    for (int d = 0; d < 256; d += 4) {
      f32x4 xa = *(const f32x4*)&As[i * 260 + d];
      f32x4 xb = *(const f32x4*)&As[j * 260 + d];
      s += xa[0] * xb[0] + xa[1] * xb[1] + xa[2] * xb[2] + xa[3] * xb[3];
    }
    if (i == j) s += 1e-6f;
    T[i * 65 + j] = s;
  }
  __syncthreads();

  if (t < 64) {
    for (int j = 0; j < 64; ++j) {
      float dj = sqrtf(T[j * 65 + j]);
      float lij = 0.f;
      if (t == j) T[j * 65 + j] = dj;
      if (t > j) { lij = T[t * 65 + j] / dj; T[t * 65 + j] = lij; }
      for (int k = j + 1; k <= t; ++k)
        T[t * 65 + k] -= lij * T[k * 65 + j];
    }
    for (int i = 0; i < 64; ++i) {
      float s = (i == t) ? 1.f : 0.f;
      for (int j = t; j < i; ++j) s -= T[i * 65 + j] * Xi[j * 65 + t];
      Xi[i * 65 + t] = (i >= t) ? s / T[i * 65 + i] : 0.f;
    }
    for (int i = 0; i < 64; ++i) {
      float v = Xi[i * 65 + t];
      unsigned u = __float_as_uint(v);
      Wtbph[i * 64 + t] = (unsigned short)(u >> 16);
      float lo = v - __uint_as_float(u & 0xFFFF0000u);
      Wtbpl[i * 64 + t] = (unsigned short)(__float_as_uint(lo) >> 16);
    }
  }
  __syncthreads();

  {
    const int i = t & 63;
    const int grp = t >> 6;
    float xrow[64];
#pragma unroll
    for (int j = 0; j < 64; ++j) xrow[j] = Xi[i * 65 + j];
    for (int c = 0; c < 4; ++c) {
      const int d0 = 8 * grp + 64 * c;
      float acc[8] = {};
#pragma unroll
      for (int j = 0; j < 64; ++j) {
        f32x4 a0 = *(const f32x4*)&As[j * 260 + d0];
        f32x4 a1 = *(const f32x4*)&As[j * 260 + d0 + 4];
        float x = xrow[j];
        acc[0] += x * a0[0]; acc[1] += x * a0[1];
        acc[2] += x * a0[2]; acc[3] += x * a0[3];
        acc[4] += x * a1[0]; acc[5] += x * a1[1];
        acc[6] += x * a1[2]; acc[7] += x * a1[3];
      }
      *(f32x4*)&G_out[i * 256 + d0] = (f32x4){acc[0], acc[1], acc[2], acc[3]};
      *(f32x4*)&G_out[i * 256 + d0 + 4] = (f32x4){acc[4], acc[5], acc[6], acc[7]};
    }
  }
}

// ---------------- gemm_mfma v2: Y = act(A @ W + bias), 3-split bf16 MFMA ----
// 32 rows/block, 512 blocks, 512 thr (8 waves, 2/SIMD, 2 blocks/CU).
__global__ __launch_bounds__(512) void gemm_mfma(
    const float* __restrict__ Af, const unsigned short* __restrict__ Ah,
    const unsigned short* __restrict__ Al, int lda,
    const unsigned short* __restrict__ Wth, const unsigned short* __restrict__ Wtl,
    const float* __restrict__ bias, float* __restrict__ Yf,
    unsigned short* __restrict__ Yh, unsigned short* __restrict__ Yl,
    int ldout, int N, int NP, int ksteps, int relu) {
  __shared__ __align__(16) unsigned short Xh_s[32][40], Xl_s[32][40];
  __shared__ __align__(16) unsigned short Wh_s[256][40], Wl_s[256][40];

  const int t = threadIdx.x, wv = t >> 6, lane = t & 63;
  const int lhi = lane >> 4, llo = lane & 15;
  const int row0 = blockIdx.x * 32;
  const int ntiles = NP >> 4;
  const int KPw = ksteps * 32;
  const int srow = t >> 2, sk8 = (t & 3) * 8;  // X stage (t < 128)
  const int wn = t >> 1, wh = (t & 1) * 16;    // W stage (all 512)

  f32x4 acc[2][2];
#pragma unroll
  for (int mt = 0; mt < 2; ++mt)
#pragma unroll
    for (int i = 0; i < 2; ++i) acc[mt][i] = (f32x4){0.f, 0.f, 0.f, 0.f};

  for (int kc = 0; kc < ksteps; ++kc) {
    const int k0 = kc * 32;
    if (kc) __syncthreads();
    if (t < 128) {
      if (Af) {
        f32x4 v0 = *(const f32x4*)&Af[(size_t)(row0 + srow) * lda + k0 + sk8];
        f32x4 v1 = *(const f32x4*)&Af[(size_t)(row0 + srow) * lda + k0 + sk8 + 4];
        short8 hv, lv;
        split2x4(v0, v1, hv, lv);
        *(short8*)&Xh_s[srow][sk8] = hv;
        *(short8*)&Xl_s[srow][sk8] = lv;
      } else {
        *(short8*)&Xh_s[srow][sk8] = *(const short8*)&Ah[(size_t)(row0 + srow) * lda + k0 + sk8];
        *(short8*)&Xl_s[srow][sk8] = *(const short8*)&Al[(size_t)(row0 + srow) * lda + k0 + sk8];
      }
    }
    if (wn < NP) {
      const u32x4* sh = (const u32x4*)&Wth[(size_t)wn * KPw + k0 + wh];
      const u32x4* sl = (const u32x4*)&Wtl[(size_t)wn * KPw + k0 + wh];
      u32x4 h0 = sh[0], h1 = sh[1], l0 = sl[0], l1 = sl[1];
      *(u32x4*)&Wh_s[wn][wh] = h0; *(u32x4*)&Wh_s[wn][wh + 8] = h1;
      *(u32x4*)&Wl_s[wn][wh] = l0; *(u32x4*)&Wl_s[wn][wh + 8] = l1;
    }
    __syncthreads();
    short8 Axh[2], Axl[2];
#pragma unroll
    for (int mt = 0; mt < 2; ++mt) {
      Axh[mt] = *(const short8*)&Xh_s[16 * mt + llo][8 * lhi];
      Axl[mt] = *(const short8*)&Xl_s[16 * mt + llo][8 * lhi];
    }
#pragma unroll
    for (int i = 0; i < 2; ++i) {
      int nt = wv + 8 * i;
      if (nt < ntiles) {
        short8 Bh = *(const short8*)&Wh_s[16 * nt + llo][8 * lhi];
        short8 Bl = *(const short8*)&Wl_s[16 * nt + llo][8 * lhi];
#pragma unroll
        for (int mt = 0; mt < 2; ++mt) {
          acc[mt][i] = mfma16(Axh[mt], Bh, acc[mt][i]);
          acc[mt][i] = mfma16(Axl[mt], Bh, acc[mt][i]);
          acc[mt][i] = mfma16(Axh[mt], Bl, acc[mt][i]);
        }
      }
    }
  }

#pragma unroll
  for (int i = 0; i < 2; ++i) {
    int nt = wv + 8 * i;
    if (nt >= ntiles) continue;
    int col = 16 * nt + llo;
    float bv = (bias && col < N) ? bias[col] : 0.f;
#pragma unroll
    for (int mt = 0; mt < 2; ++mt) {
      f32x4 c = acc[mt][i];
      int rowb = row0 + 16 * mt + 4 * lhi;
#pragma unroll
      for (int reg = 0; reg < 4; ++reg) {
        float v = c[reg] + bv;
        if (relu) v = fmaxf(v, 0.f);
        if (col >= N) v = 0.f;
        if (Yf) {
          if (col < N) Yf[(size_t)(rowb + reg) * ldout + col] = v;
        } else {
          unsigned u = __float_as_uint(v);
          float lo = v - __uint_as_float(u & 0xFFFF0000u);
          Yh[(size_t)(rowb + reg) * ldout + col] = (unsigned short)(u >> 16);
          Yl[(size_t)(rowb + reg) * ldout + col] =
              (unsigned short)(__float_as_uint(lo) >> 16);
        }
      }
    }
  }
}

// ---------------- ITER: fused 100x DR on MFMA (R13 body, unchanged) --------
__global__ __launch_bounds__(256) __attribute__((amdgpu_waves_per_eu(2, 2)))
void iter_kernel(const float* __restrict__ y0,
                 const float* __restrict__ Gg,
                 const float* __restrict__ bMg,
                 const unsigned short* __restrict__ Wtbph,
                 const unsigned short* __restrict__ Wtbpl,
                 const float* __restrict__ lb,
                 const float* __restrict__ ub,
                 const int* __restrict__ n_iter_p,
                 float* __restrict__ out) {
  __shared__ __align__(16) float wbuf[32 * 256];     // 32 KB [row][d] f32, granule-XOR
  __shared__ __align__(16) float part[4 * 32 * 68];  // 34 KB [kq][row][m]
  __shared__ __align__(16) unsigned rs[2 * 32 * 32]; // 8 KB [plane][row][32u32], XOR

  const int t = threadIdx.x, wv = t >> 6, lane = t & 63;
  const int l31 = lane & 31, h = lane >> 5;
  const int lhi = lane >> 4, llo = lane & 15;
  const int R0 = blockIdx.x * 32;
  const int n_iter = n_iter_p[0];

  // ---- bp prologue: bp[32][64] = bM[R0..][64] @ Linv^T via mfma16 ----
  f32x4 bcc[2];
  bcc[0] = (f32x4){0.f, 0.f, 0.f, 0.f};
  bcc[1] = (f32x4){0.f, 0.f, 0.f, 0.f};
#pragma unroll
  for (int ks = 0; ks < 2; ++ks) {
    short8 Bh = *(const short8*)&Wtbph[(16 * wv + llo) * 64 + 32 * ks + 8 * lhi];
    short8 Bl = *(const short8*)&Wtbpl[(16 * wv + llo) * 64 + 32 * ks + 8 * lhi];
#pragma unroll
    for (int mt = 0; mt < 2; ++mt) {
      const float* ap = &bMg[(size_t)(R0 + 16 * mt + llo) * 64 + 32 * ks + 8 * lhi];
      short8 Ah_, Al_;
      split2x4(*(const f32x4*)ap, *(const f32x4*)(ap + 4), Ah_, Al_);
      bcc[mt] = mfma16(Ah_, Bh, bcc[mt]);
      bcc[mt] = mfma16(Al_, Bh, bcc[mt]);
      bcc[mt] = mfma16(Ah_, Bl, bcc[mt]);
    }
  }
#pragma unroll
  for (int mt = 0; mt < 2; ++mt)
#pragma unroll
    for (int reg = 0; reg < 4; ++reg)
      part[(16 * mt + 4 * lhi + reg) * 64 + 16 * wv + llo] = bcc[mt][reg];
  __syncthreads();
  const int rrow = t >> 3, m8 = (t & 7) * 8;
  f32x4 bpr0 = *(const f32x4*)&part[rrow * 64 + m8];
  f32x4 bpr1 = *(const f32x4*)&part[rrow * 64 + m8 + 4];

  // ---- MV1 A-frags (32x32): GA[mt][ks] = G[32mt + l31][64wv + 16ks + 8h + j]
  short8 GAh[2][4], GAl[2][4];
#pragma unroll
  for (int mt = 0; mt < 2; ++mt)
#pragma unroll
    for (int ks = 0; ks < 4; ++ks) {
      const float* gp = &Gg[(32 * mt + l31) * 256 + 64 * wv + 16 * ks + 8 * h];
      split2x4(*(const f32x4*)gp, *(const f32x4*)(gp + 4), GAh[mt][ks], GAl[mt][ks]);
    }
  // ---- MV2 A-frags (16x16): GB[td][ks2] = G[32ks2 + 8lhi + j][64wv + 16td + llo]
  short8 GBh[4][2], GBl[4][2];
#pragma unroll
  for (int td = 0; td < 4; ++td)
#pragma unroll
    for (int ks2 = 0; ks2 < 2; ++ks2) {
      f32x4 fa, fb;
#pragma unroll
      for (int j = 0; j < 4; ++j) {
        fa[j] = Gg[(32 * ks2 + 8 * lhi + j) * 256 + 64 * wv + 16 * td + llo];
        fb[j] = Gg[(32 * ks2 + 8 * lhi + 4 + j) * 256 + 64 * wv + 16 * td + llo];
      }
      split2x4(fa, fb, GBh[td][ks2], GBl[td][ks2]);
    }

  // ---- bounds (z layout) ----
  f32x4 lbr[4], ubr[4];
#pragma unroll
  for (int td = 0; td < 4; ++td) {
    lbr[td] = *(const f32x4*)&lb[64 * wv + 16 * td + 4 * lhi];
    ubr[td] = *(const f32x4*)&ub[64 * wv + 16 * td + 4 * lhi];
  }

  // ---- precomputed LDS byte addresses ----
  int waddr[2][4];
  {
    int r3 = llo & 7;
#pragma unroll
    for (int tr = 0; tr < 2; ++tr)
#pragma unroll
      for (int td = 0; td < 4; ++td)
        waddr[tr][td] = (16 * tr + llo) * 1024 + 16 * (((16 * wv + 4 * td + lhi) ^ r3));
  }
  int raddr[4];
  {
    int r3 = l31 & 7;
#pragma unroll
    for (int ks = 0; ks < 4; ++ks)
      raddr[ks] = l31 * 1024 + 16 * ((16 * wv + 4 * ks + 2 * h) ^ r3);
  }
  const int pbase = ((wv * 32 + l31) * 68 + 4 * h) * 4;
  const int prd = (rrow * 68 + m8) * 4;
  const int rwr = rrow * 128 + 16 * ((t & 7) ^ (rrow & 7));
  int rrd[2][2];
  {
    int r3 = llo & 7;
#pragma unroll
    for (int tr = 0; tr < 2; ++tr)
#pragma unroll
      for (int ks2 = 0; ks2 < 2; ++ks2)
        rrd[tr][ks2] = (16 * tr + llo) * 128 + 16 * ((4 * ks2 + lhi) ^ r3);
  }

  // ---- z init + first w ----
  f32x4 z[4][2];
#pragma unroll
  for (int tr = 0; tr < 2; ++tr)
#pragma unroll
    for (int td = 0; td < 4; ++td) {
      f32x4 v = *(const f32x4*)&y0[(R0 + 16 * tr + llo) * 256 + 64 * wv + 16 * td + 4 * lhi];
      z[td][tr] = v;
      f32x4 wq;
#pragma unroll
      for (int e = 0; e < 4; ++e) {
        float p = med3(v[e], lbr[td][e], ubr[td][e]);
        wq[e] = (n_iter == 0) ? p : fmaf(2.f, p, -v[e]);
      }
      *(f32x4*)((char*)wbuf + waddr[tr][td]) = wq;
    }
  __syncthreads();  // also orders bpr reads before loop's part stores

  for (int it = 0; it <= n_iter; ++it) {
    // ---- MV1: partial r^T = G @ w^T over this wave's k-quarter ----
    f32x16 acc0 = {}, acc1 = {};
#pragma unroll
    for (int ks = 0; ks < 4; ++ks) {
      f32x4 f0 = *(const f32x4*)((const char*)wbuf + raddr[ks]);
      f32x4 f1 = *(const f32x4*)((const char*)wbuf + (raddr[ks] ^ 16));
      short8 Bh, Bl;
      split2x4(f0, f1, Bh, Bl);
      __builtin_amdgcn_s_setprio(1);
      acc0 = mfma32(GAh[0][ks], Bh, acc0);
      acc0 = mfma32(GAh[0][ks], Bl, acc0);
      acc0 = mfma32(GAl[0][ks], Bh, acc0);
      acc1 = mfma32(GAh[1][ks], Bh, acc1);
      acc1 = mfma32(GAh[1][ks], Bl, acc1);
      acc1 = mfma32(GAl[1][ks], Bh, acc1);
      __builtin_amdgcn_s_setprio(0);
    }
#pragma unroll
    for (int u = 0; u < 4; ++u) {
      f32x4 q0 = {acc0[4 * u], acc0[4 * u + 1], acc0[4 * u + 2], acc0[4 * u + 3]};
      f32x4 q1 = {acc1[4 * u], acc1[4 * u + 1], acc1[4 * u + 2], acc1[4 * u + 3]};
      *(f32x4*)((char*)part + (pbase + 32 * u)) = q0;
      *(f32x4*)((char*)part + (pbase + 32 * u + 128)) = q1;
    }
    __syncthreads();

    // ---- reduce 4 k-partials, -b', pack to bf16 hi/lo planes ----
    {
      const char* pb = (const char*)part + prd;
      f32x4 s0 = *(const f32x4*)pb;
      f32x4 s1 = *(const f32x4*)(pb + 16);
      s0 += *(const f32x4*)(pb + 8704);  s1 += *(const f32x4*)(pb + 8720);
      s0 += *(const f32x4*)(pb + 17408); s1 += *(const f32x4*)(pb + 17424);
      s0 += *(const f32x4*)(pb + 26112); s1 += *(const f32x4*)(pb + 26128);
      s0 -= bpr0; s1 -= bpr1;
      u32x4 hi4 = {pack_hi(s0[0], s0[1]), pack_hi(s0[2], s0[3]),
                   pack_hi(s1[0], s1[1]), pack_hi(s1[2], s1[3])};
      float l0 = s0[0] - trunch(s0[0]), l1 = s0[1] - trunch(s0[1]);
      float l2 = s0[2] - trunch(s0[2]), l3 = s0[3] - trunch(s0[3]);
      float l4 = s1[0] - trunch(s1[0]), l5 = s1[1] - trunch(s1[1]);
      float l6 = s1[2] - trunch(s1[2]), l7 = s1[3] - trunch(s1[3]);
      u32x4 lo4 = {pack_hi(l0, l1), pack_hi(l2, l3), pack_hi(l4, l5), pack_hi(l6, l7)};
      *(u32x4*)((char*)rs + rwr) = hi4;
      *(u32x4*)((char*)rs + (rwr + 4096)) = lo4;
    }
    __syncthreads();

    // ---- MV2: corr^T = G^T @ r^T (16x16); z-update + next-w (own band) ----
#pragma unroll
    for (int tr = 0; tr < 2; ++tr) {
      short8 Rh[2], Rl[2];
#pragma unroll
      for (int ks2 = 0; ks2 < 2; ++ks2) {
        Rh[ks2] = *(const short8*)((const char*)rs + rrd[tr][ks2]);
        Rl[ks2] = *(const short8*)((const char*)rs + (rrd[tr][ks2] + 4096));
      }
      f32x4 c[4];
      __builtin_amdgcn_s_setprio(1);
#pragma unroll
      for (int td = 0; td < 4; ++td) {
        f32x4 cc = {};
        cc = mfma16(GBh[td][0], Rh[0], cc);
        cc = mfma16(GBh[td][0], Rl[0], cc);
        cc = mfma16(GBl[td][0], Rh[0], cc);
        cc = mfma16(GBh[td][1], Rh[1], cc);
        cc = mfma16(GBh[td][1], Rl[1], cc);
        cc = mfma16(GBl[td][1], Rh[1], cc);
        c[td] = cc;
      }
      __builtin_amdgcn_s_setprio(0);

      if (it < n_iter - 1) {
#pragma unroll
        for (int td = 0; td < 4; ++td) {
          f32x4 zz = z[td][tr], zn, wq;
#pragma unroll
          for (int e = 0; e < 4; ++e) {
            float p = med3(zz[e], lbr[td][e], ubr[td][e]);
            zn[e] = fmaf(1.7f, p - zz[e] - c[td][e], zz[e]);
            float pn = med3(zn[e], lbr[td][e], ubr[td][e]);
            wq[e] = fmaf(2.f, pn, -zn[e]);
          }
          z[td][tr] = zn;
          *(f32x4*)((char*)wbuf + waddr[tr][td]) = wq;
        }
      } else if (it == n_iter - 1) {
#pragma unroll
        for (int td = 0; td < 4; ++td) {
          f32x4 zz = z[td][tr], zn, wq;
#pragma unroll
          for (int e = 0; e < 4; ++e) {
            float p = med3(zz[e], lbr[td][e], ubr[td][e]);
            zn[e] = fmaf(1.7f, p - zz[e] - c[td][e], zz[e]);
            wq[e] = med3(zn[e], lbr[td][e], ubr[td][e]);  // w = p on final pass
          }
          z[td][tr] = zn;
          *(f32x4*)((char*)wbuf + waddr[tr][td]) = wq;
        }
      } else {
#pragma unroll
        for (int td = 0; td < 4; ++td) {
          f32x4 zz = z[td][tr], o;
#pragma unroll
          for (int e = 0; e < 4; ++e) {
            float p = med3(zz[e], lbr[td][e], ubr[td][e]);
            o[e] = p - c[td][e];
          }
          *(f32x4*)&out[(R0 + 16 * tr + llo) * 256 + 64 * wv + 16 * td + 4 * lhi] = o;
        }
      }
    }
    // no loop-end barrier (w-exchange is wave-private; see R5/R12 audit)
  }
}

// ---------------------------------------------------------------------------
extern "C" void kernel_launch(void* const* d_in, const int* in_sizes, int n_in,
                              void* d_out, int out_size, void* d_ws, size_t ws_size,
                              hipStream_t stream) {
  (void)in_sizes; (void)n_in; (void)out_size; (void)ws_size;
  const float* x  = (const float*)d_in[0];
  const float* bM = (const float*)d_in[1];
  const float* W1 = (const float*)d_in[2];
  const float* b1 = (const float*)d_in[3];
  const float* W2 = (const float*)d_in[4];
  const float* b2 = (const float*)d_in[5];
  const float* W3 = (const float*)d_in[6];
  const float* b3 = (const float*)d_in[7];
  const float* A  = (const float*)d_in[8];
  const float* lb = (const float*)d_in[9];
  const float* ub = (const float*)d_in[10];
  const int* n_iter = (const int*)d_in[11];
  float* out = (float*)d_out;

  // workspace layout (bytes)
  char* ws = (char*)d_ws;
  unsigned short* H1h  = (unsigned short*)(ws + 0);         // 16384*224*2
  unsigned short* H1l  = (unsigned short*)(ws + 7340032);
  unsigned short* H2h  = (unsigned short*)(ws + 14680064);
  unsigned short* H2l  = (unsigned short*)(ws + 22020096);
  float*          G    = (float*)(ws + 29360128);           // 64*256*4
  unsigned short* Wt1h = (unsigned short*)(ws + 29425664);  // 224*256*2
  unsigned short* Wt1l = (unsigned short*)(ws + 29540352);
  unsigned short* Wt2h = (unsigned short*)(ws + 29655040);  // 224*224*2
  unsigned short* Wt2l = (unsigned short*)(ws + 29755392);
  unsigned short* Wt3h = (unsigned short*)(ws + 29855744);  // 256*224*2
  unsigned short* Wt3l = (unsigned short*)(ws + 29970432);
  unsigned short* Wtbph = (unsigned short*)(ws + 30085120); // 64*64*2
  unsigned short* Wtbpl = (unsigned short*)(ws + 30093312);
  float* y = out;  // stage y in d_out (fully overwritten by iter)

  // fused prep (block 0) + weight transpose (blocks 1..322)
  hipLaunchKernelGGL(prep_transw, dim3(323), dim3(512), 0, stream,
                     A, G, Wtbph, Wtbpl, W1, W2, W3,
                     Wt1h, Wt1l, Wt2h, Wt2l, Wt3h, Wt3l);

  // layer 1: x[16384][256] @ W1 -> H1 planes [16384][224]
  hipLaunchKernelGGL(gemm_mfma, dim3(512), dim3(512), 0, stream,
                     x, (const unsigned short*)nullptr, (const unsigned short*)nullptr, 256,
                     Wt1h, Wt1l, b1, (float*)nullptr, H1h, H1l, 224, 200, 224, 8, 1);
  // layer 2: H1 @ W2 -> H2 planes
  hipLaunchKernelGGL(gemm_mfma, dim3(512), dim3(512), 0, stream,
                     (const float*)nullptr, H1h, H1l, 224,
                     Wt2h, Wt2l, b2, (float*)nullptr, H2h, H2l, 224, 200, 224, 7, 1);
  // layer 3: H2 @ W3 -> y (= d_out) f32
  hipLaunchKernelGGL(gemm_mfma, dim3(512), dim3(512), 0, stream,
                     (const float*)nullptr, H2h, H2l, 224,
                     Wt3h, Wt3l, b3, y, (unsigned short*)nullptr, (unsigned short*)nullptr,
                     256, 256, 256, 7, 0);

  hipLaunchKernelGGL(iter_kernel, dim3(512), dim3(256), 0, stream,
                     y, G, bM, Wtbph, Wtbpl, lb, ub, n_iter, out);
}

// Round 15
// 480.590 us; speedup vs baseline: 1.5070x; 1.2067x over previous
//
#include <hip/hip_runtime.h>

// ---------------------------------------------------------------------------
// HardConstrainedMLP: 3-layer MLP -> 100 relaxed DR iterations -> P_eq(P_box)
// R15: symmetric-inverse formulation — H = (A A^T + 1e-6 I)^-1 via fully
//      parallel Newton-Schulz (12 steps, fp32, 512 thr), HA = H@A.
//      corr(w) = (w@A^T - b)@HA: MV1 frags from A, MV2 frags from HA,
//      b' == b (Linv / bp planes / iter bp-prologue all DELETED — this
//      removes the serial Cholesky straggler diagnosed as ~100us of the
//      197us non-iter section). iter loop body = R12 (380us verified).
// ---------------------------------------------------------------------------

typedef float f32x4 __attribute__((ext_vector_type(4)));
typedef float f32x16 __attribute__((ext_vector_type(16)));
typedef unsigned u32x4 __attribute__((ext_vector_type(4)));
typedef short short8 __attribute__((ext_vector_type(8)));

__device__ __forceinline__ unsigned pack_hi(float a, float b) {
  // (bf16bits(b) << 16) | bf16bits(a)
  return __builtin_amdgcn_perm(__float_as_uint(b), __float_as_uint(a), 0x07060302u);
}
__device__ __forceinline__ float trunch(float x) {
  return __uint_as_float(__float_as_uint(x) & 0xFFFF0000u);
}
__device__ __forceinline__ float med3(float x, float lo, float hi) {
  return __builtin_amdgcn_fmed3f(x, lo, hi);
}
__device__ __forceinline__ void split2x4(f32x4 a, f32x4 b, short8& hi, short8& lo) {
  union { unsigned u[4]; short8 v; } H, L;
  H.u[0] = pack_hi(a[0], a[1]); H.u[1] = pack_hi(a[2], a[3]);
  H.u[2] = pack_hi(b[0], b[1]); H.u[3] = pack_hi(b[2], b[3]);
  float l0 = a[0] - trunch(a[0]), l1 = a[1] - trunch(a[1]);
  float l2 = a[2] - trunch(a[2]), l3 = a[3] - trunch(a[3]);
  float l4 = b[0] - trunch(b[0]), l5 = b[1] - trunch(b[1]);
  float l6 = b[2] - trunch(b[2]), l7 = b[3] - trunch(b[3]);
  L.u[0] = pack_hi(l0, l1); L.u[1] = pack_hi(l2, l3);
  L.u[2] = pack_hi(l4, l5); L.u[3] = pack_hi(l6, l7);
  hi = H.v; lo = L.v;
}
__device__ __forceinline__ f32x4 mfma16(short8 a, short8 b, f32x4 c) {
  return __builtin_amdgcn_mfma_f32_16x16x32_bf16(a, b, c, 0, 0, 0);
}
__device__ __forceinline__ f32x16 mfma32(short8 a, short8 b, f32x16 c) {
  return __builtin_amdgcn_mfma_f32_32x32x16_bf16(a, b, c, 0, 0, 0);
}

// ---------------- fused prep (block 0) + weight transpose (blocks 1..) ------
// prep: M = AAT + eps*I; H = M^-1 via Newton-Schulz (12 steps, all-parallel);
//       HA = H @ A -> global. transw: W[K][N] f32 -> Wt[n][k] bf16 planes.
__global__ __launch_bounds__(512) void prep_transw(
    const float* __restrict__ A, float* __restrict__ HAg,
    const float* __restrict__ W1, const float* __restrict__ W2,
    const float* __restrict__ W3,
    unsigned short* __restrict__ T1h, unsigned short* __restrict__ T1l,
    unsigned short* __restrict__ T2h, unsigned short* __restrict__ T2l,
    unsigned short* __restrict__ T3h, unsigned short* __restrict__ T3l) {
  const int t = threadIdx.x;
  if (blockIdx.x != 0) {
    const int b = blockIdx.x - 1;
    const float* W; unsigned short *Th, *Tl; int K, N, KP, NP, base;
    if (b < 112)      { W = W1; Th = T1h; Tl = T1l; K = 256; N = 200; KP = 256; NP = 224; base = b; }
    else if (b < 210) { W = W2; Th = T2h; Tl = T2l; K = 200; N = 200; KP = 224; NP = 224; base = b - 112; }
    else              { W = W3; Th = T3h; Tl = T3l; K = 200; N = 256; KP = 224; NP = 256; base = b - 210; }
    int idx = base * 512 + t;
    if (idx >= NP * KP) return;
    int n = idx / KP, k = idx - n * KP;
    float v = (n < N && k < K) ? W[k * N + n] : 0.f;
    unsigned u = __float_as_uint(v);
    Th[idx] = (unsigned short)(u >> 16);
    float lo = v - __uint_as_float(u & 0xFFFF0000u);
    Tl[idx] = (unsigned short)(__float_as_uint(lo) >> 16);
    return;
  }

  __shared__ float As[64 * 260];   // A rows (16B-aligned stride)
  __shared__ float Ms[64 * 68];    // M = AAT + eps (68*4 = 272 = 16B-aligned)
  __shared__ float Xb[64 * 68], Yb[64 * 68], Zb[64 * 68];
  __shared__ float nrm[64];

  // 1. load A
  for (int q = 0; q < 8; ++q) {
    int f = 4 * (t + 512 * q);
    f32x4 v = *(const f32x4*)&A[f];
    int m = f >> 8, d = f & 255;
    *(f32x4*)&As[m * 260 + d] = v;
  }
  __syncthreads();

  // 2. M = A A^T + 1e-6 I
  for (int q = 0; q < 8; ++q) {
    int f = t + 512 * q;
    int i = f >> 6, j = f & 63;
    float s = 0.f;
    for (int d = 0; d < 256; d += 4) {
      f32x4 xa = *(const f32x4*)&As[i * 260 + d];
      f32x4 xb = *(const f32x4*)&As[j * 260 + d];
      s += xa[0] * xb[0] + xa[1] * xb[1] + xa[2] * xb[2] + xa[3] * xb[3];
    }
    if (i == j) s += 1e-6f;
    Ms[i * 68 + j] = s;
  }
  __syncthreads();

  // 3. alpha = 1 / max row 1-norm (Gershgorin bound on lambda_max)
  if (t < 64) {
    float s = 0.f;
    for (int j = 0; j < 64; ++j) s += fabsf(Ms[t * 68 + j]);
    nrm[t] = s;
  }
  __syncthreads();
  float mx = 0.f;
#pragma unroll
  for (int j = 0; j < 64; ++j) mx = fmaxf(mx, nrm[j]);
  const float alpha = 1.0f / mx;

  // 4. X0 = alpha * I
  const int ri = t >> 3, j0 = (t & 7) * 8;
#pragma unroll
  for (int e = 0; e < 8; ++e) Xb[ri * 68 + j0 + e] = (ri == j0 + e) ? alpha : 0.f;
  __syncthreads();

  // 5. Newton-Schulz: X <- X (2I - M X), 12 doublings (fp32, fully parallel)
  float* Xp = Xb;
  float* Zp = Zb;
  for (int itn = 0; itn < 12; ++itn) {
    // Y = M @ X
    f32x4 a0 = {0.f, 0.f, 0.f, 0.f}, a1 = {0.f, 0.f, 0.f, 0.f};
    for (int k4 = 0; k4 < 16; ++k4) {
      f32x4 mv = *(const f32x4*)&Ms[ri * 68 + 4 * k4];
#pragma unroll
      for (int e = 0; e < 4; ++e) {
        int k = 4 * k4 + e;
        f32x4 x0 = *(const f32x4*)&Xp[k * 68 + j0];
        f32x4 x1 = *(const f32x4*)&Xp[k * 68 + j0 + 4];
        a0 += mv[e] * x0;
        a1 += mv[e] * x1;
      }
    }
    *(f32x4*)&Yb[ri * 68 + j0] = a0;
    *(f32x4*)&Yb[ri * 68 + j0 + 4] = a1;
    __syncthreads();
    // Z = 2X - X @ Y
    a0 = (f32x4){0.f, 0.f, 0.f, 0.f};
    a1 = (f32x4){0.f, 0.f, 0.f, 0.f};
    for (int k4 = 0; k4 < 16; ++k4) {
      f32x4 xv = *(const f32x4*)&Xp[ri * 68 + 4 * k4];
#pragma unroll
      for (int e = 0; e < 4; ++e) {
        int k = 4 * k4 + e;
        f32x4 y0 = *(const f32x4*)&Yb[k * 68 + j0];
        f32x4 y1 = *(const f32x4*)&Yb[k * 68 + j0 + 4];
        a0 += xv[e] * y0;
        a1 += xv[e] * y1;
      }
    }
    f32x4 x0 = *(const f32x4*)&Xp[ri * 68 + j0];
    f32x4 x1 = *(const f32x4*)&Xp[ri * 68 + j0 + 4];
    *(f32x4*)&Zp[ri * 68 + j0] = 2.f * x0 - a0;
    *(f32x4*)&Zp[ri * 68 + j0 + 4] = 2.f * x1 - a1;
    __syncthreads();
    float* tmp = Xp; Xp = Zp; Zp = tmp;
  }

  // 6. HA = H @ A -> global (H = Xp)
  {
    const int i = t & 63;
    const int grp = t >> 6;
    float hrow[64];
#pragma unroll
    for (int j = 0; j < 64; ++j) hrow[j] = Xp[i * 68 + j];
    for (int c = 0; c < 4; ++c) {
      const int d0 = 8 * grp + 64 * c;
      float acc[8] = {};
#pragma unroll
      for (int j = 0; j < 64; ++j) {
        f32x4 a0 = *(const f32x4*)&As[j * 260 + d0];
        f32x4 a1 = *(const f32x4*)&As[j * 260 + d0 + 4];
        float x = hrow[j];
        acc[0] += x * a0[0]; acc[1] += x * a0[1];
        acc[2] += x * a0[2]; acc[3] += x * a0[3];
        acc[4] += x * a1[0]; acc[5] += x * a1[1];
        acc[6] += x * a1[2]; acc[7] += x * a1[3];
      }
      *(f32x4*)&HAg[i * 256 + d0] = (f32x4){acc[0], acc[1], acc[2], acc[3]};
      *(f32x4*)&HAg[i * 256 + d0 + 4] = (f32x4){acc[4], acc[5], acc[6], acc[7]};
    }
  }
}

// ---------------- gemm_mfma: Y = act(A @ W + bias), 3-split bf16 MFMA -------
// 32 rows/block, 512 blocks, 512 thr (8 waves, 2/SIMD, 2 blocks/CU).
__global__ __launch_bounds__(512) void gemm_mfma(
    const float* __restrict__ Af, const unsigned short* __restrict__ Ah,
    const unsigned short* __restrict__ Al, int lda,
    const unsigned short* __restrict__ Wth, const unsigned short* __restrict__ Wtl,
    const float* __restrict__ bias, float* __restrict__ Yf,
    unsigned short* __restrict__ Yh, unsigned short* __restrict__ Yl,
    int ldout, int N, int NP, int ksteps, int relu) {
  __shared__ __align__(16) unsigned short Xh_s[32][40], Xl_s[32][40];
  __shared__ __align__(16) unsigned short Wh_s[256][40], Wl_s[256][40];

  const int t = threadIdx.x, wv = t >> 6, lane = t & 63;
  const int lhi = lane >> 4, llo = lane & 15;
  const int row0 = blockIdx.x * 32;
  const int ntiles = NP >> 4;
  const int KPw = ksteps * 32;
  const int srow = t >> 2, sk8 = (t & 3) * 8;  // X stage (t < 128)
  const int wn = t >> 1, wh = (t & 1) * 16;    // W stage (all 512)

  f32x4 acc[2][2];
#pragma unroll
  for (int mt = 0; mt < 2; ++mt)
#pragma unroll
    for (int i = 0; i < 2; ++i) acc[mt][i] = (f32x4){0.f, 0.f, 0.f, 0.f};

  for (int kc = 0; kc < ksteps; ++kc) {
    const int k0 = kc * 32;
    if (kc) __syncthreads();
    if (t < 128) {
      if (Af) {
        f32x4 v0 = *(const f32x4*)&Af[(size_t)(row0 + srow) * lda + k0 + sk8];
        f32x4 v1 = *(const f32x4*)&Af[(size_t)(row0 + srow) * lda + k0 + sk8 + 4];
        short8 hv, lv;
        split2x4(v0, v1, hv, lv);
        *(short8*)&Xh_s[srow][sk8] = hv;
        *(short8*)&Xl_s[srow][sk8] = lv;
      } else {
        *(short8*)&Xh_s[srow][sk8] = *(const short8*)&Ah[(size_t)(row0 + srow) * lda + k0 + sk8];
        *(short8*)&Xl_s[srow][sk8] = *(const short8*)&Al[(size_t)(row0 + srow) * lda + k0 + sk8];
      }
    }
    if (wn < NP) {
      const u32x4* sh = (const u32x4*)&Wth[(size_t)wn * KPw + k0 + wh];
      const u32x4* sl = (const u32x4*)&Wtl[(size_t)wn * KPw + k0 + wh];
      u32x4 h0 = sh[0], h1 = sh[1], l0 = sl[0], l1 = sl[1];
      *(u32x4*)&Wh_s[wn][wh] = h0; *(u32x4*)&Wh_s[wn][wh + 8] = h1;
      *(u32x4*)&Wl_s[wn][wh] = l0; *(u32x4*)&Wl_s[wn][wh + 8] = l1;
    }
    __syncthreads();
    short8 Axh[2], Axl[2];
#pragma unroll
    for (int mt = 0; mt < 2; ++mt) {
      Axh[mt] = *(const short8*)&Xh_s[16 * mt + llo][8 * lhi];
      Axl[mt] = *(const short8*)&Xl_s[16 * mt + llo][8 * lhi];
    }
#pragma unroll
    for (int i = 0; i < 2; ++i) {
      int nt = wv + 8 * i;
      if (nt < ntiles) {
        short8 Bh = *(const short8*)&Wh_s[16 * nt + llo][8 * lhi];
        short8 Bl = *(const short8*)&Wl_s[16 * nt + llo][8 * lhi];
#pragma unroll
        for (int mt = 0; mt < 2; ++mt) {
          acc[mt][i] = mfma16(Axh[mt], Bh, acc[mt][i]);
          acc[mt][i] = mfma16(Axl[mt], Bh, acc[mt][i]);
          acc[mt][i] = mfma16(Axh[mt], Bl, acc[mt][i]);
        }
      }
    }
  }

#pragma unroll
  for (int i = 0; i < 2; ++i) {
    int nt = wv + 8 * i;
    if (nt >= ntiles) continue;
    int col = 16 * nt + llo;
    float bv = (bias && col < N) ? bias[col] : 0.f;
#pragma unroll
    for (int mt = 0; mt < 2; ++mt) {
      f32x4 c = acc[mt][i];
      int rowb = row0 + 16 * mt + 4 * lhi;
#pragma unroll
      for (int reg = 0; reg < 4; ++reg) {
        float v = c[reg] + bv;
        if (relu) v = fmaxf(v, 0.f);
        if (col >= N) v = 0.f;
        if (Yf) {
          if (col < N) Yf[(size_t)(rowb + reg) * ldout + col] = v;
        } else {
          unsigned u = __float_as_uint(v);
          float lo = v - __uint_as_float(u & 0xFFFF0000u);
          Yh[(size_t)(rowb + reg) * ldout + col] = (unsigned short)(u >> 16);
          Yl[(size_t)(rowb + reg) * ldout + col] =
              (unsigned short)(__float_as_uint(lo) >> 16);
        }
      }
    }
  }
}

// ---------------- ITER: fused 100x DR on MFMA (R12 body; A/HA sources) -----
// 512 blocks x 256 thr (4 waves), 32 rows/block.
// MV1: r^T = A @ w^T (A row-frags); reduce: sum - b (bM direct);
// MV2: corr^T = (HA)^T @ r^T (HA col-frags) -> z layout. 2 barriers/iter.
__global__ __launch_bounds__(256) __attribute__((amdgpu_waves_per_eu(2, 2)))
void iter_kernel(const float* __restrict__ y0,
                 const float* __restrict__ Ag,
                 const float* __restrict__ HAg,
                 const float* __restrict__ bMg,
                 const float* __restrict__ lb,
                 const float* __restrict__ ub,
                 const int* __restrict__ n_iter_p,
                 float* __restrict__ out) {
  __shared__ __align__(16) float wbuf[32 * 256];     // 32 KB [row][d] f32, granule-XOR
  __shared__ __align__(16) float part[4 * 32 * 68];  // 34 KB [kq][row][m]
  __shared__ __align__(16) unsigned rs[2 * 32 * 32]; // 8 KB [plane][row][32u32], XOR

  const int t = threadIdx.x, wv = t >> 6, lane = t & 63;
  const int l31 = lane & 31, h = lane >> 5;
  const int lhi = lane >> 4, llo = lane & 15;
  const int R0 = blockIdx.x * 32;
  const int n_iter = n_iter_p[0];

  // ---- MV1 A-frags (32x32): GA[mt][ks] = A[32mt + l31][64wv + 16ks + 8h + j]
  short8 GAh[2][4], GAl[2][4];
#pragma unroll
  for (int mt = 0; mt < 2; ++mt)
#pragma unroll
    for (int ks = 0; ks < 4; ++ks) {
      const float* gp = &Ag[(32 * mt + l31) * 256 + 64 * wv + 16 * ks + 8 * h];
      split2x4(*(const f32x4*)gp, *(const f32x4*)(gp + 4), GAh[mt][ks], GAl[mt][ks]);
    }
  // ---- MV2 A-frags (16x16): GB[td][ks2] = HA[32ks2 + 8lhi + j][64wv + 16td + llo]
  short8 GBh[4][2], GBl[4][2];
#pragma unroll
  for (int td = 0; td < 4; ++td)
#pragma unroll
    for (int ks2 = 0; ks2 < 2; ++ks2) {
      f32x4 fa, fb;
#pragma unroll
      for (int j = 0; j < 4; ++j) {
        fa[j] = HAg[(32 * ks2 + 8 * lhi + j) * 256 + 64 * wv + 16 * td + llo];
        fb[j] = HAg[(32 * ks2 + 8 * lhi + 4 + j) * 256 + 64 * wv + 16 * td + llo];
      }
      split2x4(fa, fb, GBh[td][ks2], GBl[td][ks2]);
    }

  // ---- bounds (z layout) / b (reduce layout; b' == b in H-formulation) ----
  f32x4 lbr[4], ubr[4];
#pragma unroll
  for (int td = 0; td < 4; ++td) {
    lbr[td] = *(const f32x4*)&lb[64 * wv + 16 * td + 4 * lhi];
    ubr[td] = *(const f32x4*)&ub[64 * wv + 16 * td + 4 * lhi];
  }
  const int rrow = t >> 3, m8 = (t & 7) * 8;
  f32x4 bpr0 = *(const f32x4*)&bMg[(size_t)(R0 + rrow) * 64 + m8];
  f32x4 bpr1 = *(const f32x4*)&bMg[(size_t)(R0 + rrow) * 64 + m8 + 4];

  // ---- precomputed LDS byte addresses ----
  int waddr[2][4];
  {
    int r3 = llo & 7;
#pragma unroll
    for (int tr = 0; tr < 2; ++tr)
#pragma unroll
      for (int td = 0; td < 4; ++td)
        waddr[tr][td] = (16 * tr + llo) * 1024 + 16 * (((16 * wv + 4 * td + lhi) ^ r3));
  }
  int raddr[4];
  {
    int r3 = l31 & 7;
#pragma unroll
    for (int ks = 0; ks < 4; ++ks)
      raddr[ks] = l31 * 1024 + 16 * ((16 * wv + 4 * ks + 2 * h) ^ r3);
  }
  const int pbase = ((wv * 32 + l31) * 68 + 4 * h) * 4;
  const int prd = (rrow * 68 + m8) * 4;
  const int rwr = rrow * 128 + 16 * ((t & 7) ^ (rrow & 7));
  int rrd[2][2];
  {
    int r3 = llo & 7;
#pragma unroll
    for (int tr = 0; tr < 2; ++tr)
#pragma unroll
      for (int ks2 = 0; ks2 < 2; ++ks2)
        rrd[tr][ks2] = (16 * tr + llo) * 128 + 16 * ((4 * ks2 + lhi) ^ r3);
  }

  // ---- z init + first w ----
  f32x4 z[4][2];
#pragma unroll
  for (int tr = 0; tr < 2; ++tr)
#pragma unroll
    for (int td = 0; td < 4; ++td) {
      f32x4 v = *(const f32x4*)&y0[(R0 + 16 * tr + llo) * 256 + 64 * wv + 16 * td + 4 * lhi];
      z[td][tr] = v;
      f32x4 wq;
#pragma unroll
      for (int e = 0; e < 4; ++e) {
        float p = med3(v[e], lbr[td][e], ubr[td][e]);
        wq[e] = (n_iter == 0) ? p : fmaf(2.f, p, -v[e]);
      }
      *(f32x4*)((char*)wbuf + waddr[tr][td]) = wq;
    }
  __syncthreads();

  for (int it = 0; it <= n_iter; ++it) {
    // ---- MV1: partial r^T = A @ w^T over this wave's k-quarter ----
    f32x16 acc0 = {}, acc1 = {};
#pragma unroll
    for (int ks = 0; ks < 4; ++ks) {
      f32x4 f0 = *(const f32x4*)((const char*)wbuf + raddr[ks]);
      f32x4 f1 = *(const f32x4*)((const char*)wbuf + (raddr[ks] ^ 16));
      short8 Bh, Bl;
      split2x4(f0, f1, Bh, Bl);
      __builtin_amdgcn_s_setprio(1);
      acc0 = mfma32(GAh[0][ks], Bh, acc0);
      acc0 = mfma32(GAh[0][ks], Bl, acc0);
      acc0 = mfma32(GAl[0][ks], Bh, acc0);
      acc1 = mfma32(GAh[1][ks], Bh, acc1);
      acc1 = mfma32(GAh[1][ks], Bl, acc1);
      acc1 = mfma32(GAl[1][ks], Bh, acc1);
      __builtin_amdgcn_s_setprio(0);
    }
#pragma unroll
    for (int u = 0; u < 4; ++u) {
      f32x4 q0 = {acc0[4 * u], acc0[4 * u + 1], acc0[4 * u + 2], acc0[4 * u + 3]};
      f32x4 q1 = {acc1[4 * u], acc1[4 * u + 1], acc1[4 * u + 2], acc1[4 * u + 3]};
      *(f32x4*)((char*)part + (pbase + 32 * u)) = q0;
      *(f32x4*)((char*)part + (pbase + 32 * u + 128)) = q1;
    }
    __syncthreads();

    // ---- reduce 4 k-partials, -b, pack to bf16 hi/lo planes ----
    {
      const char* pb = (const char*)part + prd;
      f32x4 s0 = *(const f32x4*)pb;
      f32x4 s1 = *(const f32x4*)(pb + 16);
      s0 += *(const f32x4*)(pb + 8704);  s1 += *(const f32x4*)(pb + 8720);
      s0 += *(const f32x4*)(pb + 17408); s1 += *(const f32x4*)(pb + 17424);
      s0 += *(const f32x4*)(pb + 26112); s1 += *(const f32x4*)(pb + 26128);
      s0 -= bpr0; s1 -= bpr1;
      u32x4 hi4 = {pack_hi(s0[0], s0[1]), pack_hi(s0[2], s0[3]),
                   pack_hi(s1[0], s1[1]), pack_hi(s1[2], s1[3])};
      float l0 = s0[0] - trunch(s0[0]), l1 = s0[1] - trunch(s0[1]);
      float l2 = s0[2] - trunch(s0[2]), l3 = s0[3] - trunch(s0[3]);
      float l4 = s1[0] - trunch(s1[0]), l5 = s1[1] - trunch(s1[1]);
      float l6 = s1[2] - trunch(s1[2]), l7 = s1[3] - trunch(s1[3]);
      u32x4 lo4 = {pack_hi(l0, l1), pack_hi(l2, l3), pack_hi(l4, l5), pack_hi(l6, l7)};
      *(u32x4*)((char*)rs + rwr) = hi4;
      *(u32x4*)((char*)rs + (rwr + 4096)) = lo4;
    }
    __syncthreads();

    // ---- MV2: corr^T = (HA)^T @ r^T (16x16); z-update + next-w ----
#pragma unroll
    for (int tr = 0; tr < 2; ++tr) {
      short8 Rh[2], Rl[2];
#pragma unroll
      for (int ks2 = 0; ks2 < 2; ++ks2) {
        Rh[ks2] = *(const short8*)((const char*)rs + rrd[tr][ks2]);
        Rl[ks2] = *(const short8*)((const char*)rs + (rrd[tr][ks2] + 4096));
      }
      f32x4 c[4];
      __builtin_amdgcn_s_setprio(1);
#pragma unroll
      for (int td = 0; td < 4; ++td) {
        f32x4 cc = {};
        cc = mfma16(GBh[td][0], Rh[0], cc);
        cc = mfma16(GBh[td][0], Rl[0], cc);
        cc = mfma16(GBl[td][0], Rh[0], cc);
        cc = mfma16(GBh[td][1], Rh[1], cc);
        cc = mfma16(GBh[td][1], Rl[1], cc);
        cc = mfma16(GBl[td][1], Rh[1], cc);
        c[td] = cc;
      }
      __builtin_amdgcn_s_setprio(0);

      if (it < n_iter - 1) {
#pragma unroll
        for (int td = 0; td < 4; ++td) {
          f32x4 zz = z[td][tr], zn, wq;
#pragma unroll
          for (int e = 0; e < 4; ++e) {
            float p = med3(zz[e], lbr[td][e], ubr[td][e]);
            zn[e] = fmaf(1.7f, p - zz[e] - c[td][e], zz[e]);
            float pn = med3(zn[e], lbr[td][e], ubr[td][e]);
            wq[e] = fmaf(2.f, pn, -zn[e]);
          }
          z[td][tr] = zn;
          *(f32x4*)((char*)wbuf + waddr[tr][td]) = wq;
        }
      } else if (it == n_iter - 1) {
#pragma unroll
        for (int td = 0; td < 4; ++td) {
          f32x4 zz = z[td][tr], zn, wq;
#pragma unroll
          for (int e = 0; e < 4; ++e) {
            float p = med3(zz[e], lbr[td][e], ubr[td][e]);
            zn[e] = fmaf(1.7f, p - zz[e] - c[td][e], zz[e]);
            wq[e] = med3(zn[e], lbr[td][e], ubr[td][e]);  // w = p on final pass
          }
          z[td][tr] = zn;
          *(f32x4*)((char*)wbuf + waddr[tr][td]) = wq;
        }
      } else {
#pragma unroll
        for (int td = 0; td < 4; ++td) {
          f32x4 zz = z[td][tr], o;
#pragma unroll
          for (int e = 0; e < 4; ++e) {
            float p = med3(zz[e], lbr[td][e], ubr[td][e]);
            o[e] = p - c[td][e];
          }
          *(f32x4*)&out[(R0 + 16 * tr + llo) * 256 + 64 * wv + 16 * td + 4 * lhi] = o;
        }
      }
    }
    // no loop-end barrier (w-exchange is wave-private; see R5/R12 audit)
  }
}

// ---------------------------------------------------------------------------
extern "C" void kernel_launch(void* const* d_in, const int* in_sizes, int n_in,
                              void* d_out, int out_size, void* d_ws, size_t ws_size,
                              hipStream_t stream) {
  (void)in_sizes; (void)n_in; (void)out_size; (void)ws_size;
  const float* x  = (const float*)d_in[0];
  const float* bM = (const float*)d_in[1];
  const float* W1 = (const float*)d_in[2];
  const float* b1 = (const float*)d_in[3];
  const float* W2 = (const float*)d_in[4];
  const float* b2 = (const float*)d_in[5];
  const float* W3 = (const float*)d_in[6];
  const float* b3 = (const float*)d_in[7];
  const float* A  = (const float*)d_in[8];
  const float* lb = (const float*)d_in[9];
  const float* ub = (const float*)d_in[10];
  const int* n_iter = (const int*)d_in[11];
  float* out = (float*)d_out;

  // workspace layout (bytes)
  char* ws = (char*)d_ws;
  unsigned short* H1h  = (unsigned short*)(ws + 0);         // 16384*224*2
  unsigned short* H1l  = (unsigned short*)(ws + 7340032);
  unsigned short* H2h  = (unsigned short*)(ws + 14680064);
  unsigned short* H2l  = (unsigned short*)(ws + 22020096);
  float*          HA   = (float*)(ws + 29360128);           // 64*256*4
  unsigned short* Wt1h = (unsigned short*)(ws + 29425664);  // 224*256*2
  unsigned short* Wt1l = (unsigned short*)(ws + 29540352);
  unsigned short* Wt2h = (unsigned short*)(ws + 29655040);  // 224*224*2
  unsigned short* Wt2l = (unsigned short*)(ws + 29755392);
  unsigned short* Wt3h = (unsigned short*)(ws + 29855744);  // 256*224*2
  unsigned short* Wt3l = (unsigned short*)(ws + 29970432);
  float* y = out;  // stage y in d_out (fully overwritten by iter)

  // fused prep (block 0: Newton-Schulz H, HA) + weight transpose (1..322)
  hipLaunchKernelGGL(prep_transw, dim3(323), dim3(512), 0, stream,
                     A, HA, W1, W2, W3,
                     Wt1h, Wt1l, Wt2h, Wt2l, Wt3h, Wt3l);

  // layer 1: x[16384][256] @ W1 -> H1 planes [16384][224]
  hipLaunchKernelGGL(gemm_mfma, dim3(512), dim3(512), 0, stream,
                     x, (const unsigned short*)nullptr, (const unsigned short*)nullptr, 256,
                     Wt1h, Wt1l, b1, (float*)nullptr, H1h, H1l, 224, 200, 224, 8, 1);
  // layer 2: H1 @ W2 -> H2 planes
  hipLaunchKernelGGL(gemm_mfma, dim3(512), dim3(512), 0, stream,
                     (const float*)nullptr, H1h, H1l, 224,
                     Wt2h, Wt2l, b2, (float*)nullptr, H2h, H2l, 224, 200, 224, 7, 1);
  // layer 3: H2 @ W3 -> y (= d_out) f32
  hipLaunchKernelGGL(gemm_mfma, dim3(512), dim3(512), 0, stream,
                     (const float*)nullptr, H2h, H2l, 224,
                     Wt3h, Wt3l, b3, y, (unsigned short*)nullptr, (unsigned short*)nullptr,
                     256, 256, 256, 7, 0);

  hipLaunchKernelGGL(iter_kernel, dim3(512), dim3(256), 0, stream,
                     y, A, HA, bM, lb, ub, n_iter, out);
}